// Round 2
// baseline (825.035 us; speedup 1.0000x reference)
//
#include <hip/hip_runtime.h>

#define BDIM 8
#define NPTS 8192
#define MPTS 2048
#define NSAMP 65536.0f

typedef __attribute__((ext_vector_type(8))) short bf16x8;
typedef __attribute__((ext_vector_type(4))) float f32x4;

static __device__ __forceinline__ unsigned short f2bf(float f) {
  unsigned int x = __float_as_uint(f);
  x += 0x7FFFu + ((x >> 16) & 1u);          // round-to-nearest-even
  return (unsigned short)(x >> 16);
}
static __device__ __forceinline__ float bf2f(unsigned short u) {
  return __uint_as_float(((unsigned int)u) << 16);
}

// ---------------------------------------------------------------------------
// three_nn: exact reference fp32 formula, strict-< insertion (earlier idx wins)
// ---------------------------------------------------------------------------
__global__ __launch_bounds__(256)
void three_nn_kernel(const float* __restrict__ xyz, const float* __restrict__ xyz_prev,
                     int* __restrict__ idx_out, float* __restrict__ wgt_out) {
  __shared__ float px[MPTS], py[MPTS], pz[MPTS], sk[MPTS];
  const int b = blockIdx.y;
  const int tid = threadIdx.x;
  for (int j = tid; j < MPTS; j += 256) {
    float x = xyz_prev[((size_t)b*MPTS + j)*3 + 0];
    float y = xyz_prev[((size_t)b*MPTS + j)*3 + 1];
    float z = xyz_prev[((size_t)b*MPTS + j)*3 + 2];
    px[j] = x; py[j] = y; pz[j] = z;
    sk[j] = __fadd_rn(__fadd_rn(__fmul_rn(x,x), __fmul_rn(y,y)), __fmul_rn(z,z));
  }
  __syncthreads();
  const int n = blockIdx.x*256 + tid;
  const size_t qoff = ((size_t)b*NPTS + n)*3;
  const float qx = xyz[qoff], qy = xyz[qoff+1], qz = xyz[qoff+2];
  const float squ = __fadd_rn(__fadd_rn(__fmul_rn(qx,qx), __fmul_rn(qy,qy)), __fmul_rn(qz,qz));

  float d0 = 3.4e38f, d1 = 3.4e38f, d2v = 3.4e38f;
  int j0 = 0, j1 = 0, j2 = 0;
  for (int m = 0; m < MPTS; ++m) {
    float dot = __fadd_rn(__fadd_rn(__fmul_rn(qx,px[m]), __fmul_rn(qy,py[m])), __fmul_rn(qz,pz[m]));
    float dd  = __fsub_rn(__fadd_rn(squ, sk[m]), __fmul_rn(2.0f, dot));
    if (dd < d2v) {
      if (dd < d1) {
        d2v = d1; j2 = j1;
        if (dd < d0) { d1 = d0; j1 = j0; d0 = dd; j0 = m; }
        else         { d1 = dd; j1 = m; }
      } else { d2v = dd; j2 = m; }
    }
  }
  const float s0 = sqrtf(fmaxf(d0, 0.f));
  const float s1 = sqrtf(fmaxf(d1, 0.f));
  const float s2 = sqrtf(fmaxf(d2v, 0.f));
  const float i0 = 1.f/(s0 + 1e-8f), i1 = 1.f/(s1 + 1e-8f), i2 = 1.f/(s2 + 1e-8f);
  const float sum = i0 + i1 + i2;
  const size_t o = ((size_t)b*NPTS + n)*3;
  idx_out[o] = j0; idx_out[o+1] = j1; idx_out[o+2] = j2;
  wgt_out[o] = i0/sum; wgt_out[o+1] = i1/sum; wgt_out[o+2] = i2/sum;
}

// ---------------------------------------------------------------------------
// fp32 -> bf16 flat convert (for weights)
// ---------------------------------------------------------------------------
__global__ __launch_bounds__(256)
void cvt_kernel(const float* __restrict__ s, unsigned short* __restrict__ d, int n) {
  int t = blockIdx.x*256 + threadIdx.x;
  if (t < n) d[t] = f2bf(s[t]);
}

// ---------------------------------------------------------------------------
// features [b][c][n] fp32 -> X1t[b][n][256+c] bf16 (64x64 tiled transpose)
// ---------------------------------------------------------------------------
__global__ __launch_bounds__(256)
void feat_t_kernel(const float* __restrict__ feat, unsigned short* __restrict__ X1t) {
  __shared__ __align__(16) unsigned short St[64][72];
  const int tid = threadIdx.x;
  const int n0 = blockIdx.x*64, c0 = blockIdx.y*64, b = blockIdx.z;
  const int cl = tid >> 2;
  #pragma unroll
  for (int i = 0; i < 4; ++i) {
    int nl = (tid & 3)*16 + i*4;
    float4 v = *(const float4*)&feat[((size_t)(b*256 + c0 + cl))*NPTS + n0 + nl];
    St[cl][nl]   = f2bf(v.x); St[cl][nl+1] = f2bf(v.y);
    St[cl][nl+2] = f2bf(v.z); St[cl][nl+3] = f2bf(v.w);
  }
  __syncthreads();
  #pragma unroll
  for (int i = 0; i < 2; ++i) {
    int u = tid + i*256;
    int nl = u >> 3, c8 = (u & 7)*8;
    unsigned short tmp[8];
    #pragma unroll
    for (int j = 0; j < 8; ++j) tmp[j] = St[c8 + j][nl];
    *(uint4*)&X1t[((size_t)(b*NPTS + n0 + nl))*512 + 256 + c0 + c8] = *(uint4*)tmp;
  }
}

// ---------------------------------------------------------------------------
// interpolate -> X1t[b][n][c] bf16 (c in [0,256)); thread owns one n-column,
// loops channels, packs 8 at a time for 16B coalesced-row stores.
// ---------------------------------------------------------------------------
__global__ __launch_bounds__(256)
void interp_t_kernel(const float* __restrict__ fp, const int* __restrict__ idx,
                     const float* __restrict__ wgt, unsigned short* __restrict__ X1t) {
  const int tid = threadIdx.x;
  const int b = blockIdx.y, n = blockIdx.x*256 + tid;
  const size_t p = ((size_t)b*NPTS + n)*3;
  const int i0 = idx[p], i1 = idx[p+1], i2 = idx[p+2];
  const float w0 = wgt[p], w1 = wgt[p+1], w2 = wgt[p+2];
  const float* fb = fp + (size_t)b*256*MPTS;
  unsigned short* dst = X1t + ((size_t)b*NPTS + n)*512;
  for (int c8 = 0; c8 < 256; c8 += 8) {
    unsigned short tmp[8];
    #pragma unroll
    for (int j = 0; j < 8; ++j) {
      const float* frow = fb + (size_t)(c8 + j)*MPTS;
      tmp[j] = f2bf(frow[i0]*w0 + frow[i1]*w1 + frow[i2]*w2);
    }
    *(uint4*)&dst[c8] = *(uint4*)tmp;
  }
}

// ---------------------------------------------------------------------------
// MFMA GEMM: Y[b][n][o] = sum_k W[o][k] * Xt[b][n][k]  (all bf16, fp32 acc)
// Block: 512 thr (8 waves as 4 o-groups x 2 n-groups), tile [256 o][128 n],
// K-loop BK=32, single-buffer LDS, register prefetch.
// MODE 1: apply per-k affine (scl,shf) + ReLU to X during staging (BN1 fuse).
// Epilogue: +bias, per-o sum/sumsq atomics (BN stats), bf16 store.
// ---------------------------------------------------------------------------
template<int KD, int MODE>
__global__ __launch_bounds__(512)
void gemm_t_kernel(const unsigned short* __restrict__ W, const unsigned short* __restrict__ X,
                   const float* __restrict__ bias, const float* __restrict__ scl,
                   const float* __restrict__ shf, unsigned short* __restrict__ Y,
                   float* __restrict__ bsum, float* __restrict__ bsq) {
  __shared__ __align__(16) unsigned short Ws[256*32];
  __shared__ __align__(16) unsigned short Xs[128*32];
  const int tid = threadIdx.x;
  const int b = blockIdx.y, n0 = blockIdx.x*128;
  const int row = tid >> 2, seg = tid & 3;          // 128 rows x 4 16B-segments
  const unsigned short* Xb = X + (size_t)(b*NPTS + n0)*KD;

  uint4 wv0 = *(const uint4*)&W[(size_t)row*KD + seg*8];
  uint4 wv1 = *(const uint4*)&W[(size_t)(row+128)*KD + seg*8];
  uint4 xv  = *(const uint4*)&Xb[(size_t)row*KD + seg*8];

  f32x4 acc[4][4];
  #pragma unroll
  for (int i = 0; i < 4; ++i)
    #pragma unroll
    for (int j = 0; j < 4; ++j) acc[i][j] = (f32x4){0.f,0.f,0.f,0.f};

  const int lane = tid & 63, l16 = lane & 15, quad = lane >> 4;
  const int wave = tid >> 6, wo = wave >> 1, wn = wave & 1;

  for (int kt = 0; kt < KD/32; ++kt) {
    __syncthreads();
    *(uint4*)&Ws[row*32 + seg*8]       = wv0;
    *(uint4*)&Ws[(row+128)*32 + seg*8] = wv1;
    if (MODE == 0) {
      *(uint4*)&Xs[row*32 + seg*8] = xv;
    } else {
      const int kc = kt*32 + seg*8;
      float4 s0 = *(const float4*)&scl[kc], s1 = *(const float4*)&scl[kc+4];
      float4 h0 = *(const float4*)&shf[kc], h1 = *(const float4*)&shf[kc+4];
      const unsigned short* xu = (const unsigned short*)&xv;
      unsigned short t[8];
      t[0] = f2bf(fmaxf(fmaf(bf2f(xu[0]), s0.x, h0.x), 0.f));
      t[1] = f2bf(fmaxf(fmaf(bf2f(xu[1]), s0.y, h0.y), 0.f));
      t[2] = f2bf(fmaxf(fmaf(bf2f(xu[2]), s0.z, h0.z), 0.f));
      t[3] = f2bf(fmaxf(fmaf(bf2f(xu[3]), s0.w, h0.w), 0.f));
      t[4] = f2bf(fmaxf(fmaf(bf2f(xu[4]), s1.x, h1.x), 0.f));
      t[5] = f2bf(fmaxf(fmaf(bf2f(xu[5]), s1.y, h1.y), 0.f));
      t[6] = f2bf(fmaxf(fmaf(bf2f(xu[6]), s1.z, h1.z), 0.f));
      t[7] = f2bf(fmaxf(fmaf(bf2f(xu[7]), s1.w, h1.w), 0.f));
      *(uint4*)&Xs[row*32 + seg*8] = *(uint4*)t;
    }
    __syncthreads();
    if (kt + 1 < KD/32) {
      const int k0 = (kt+1)*32;
      wv0 = *(const uint4*)&W[(size_t)row*KD + k0 + seg*8];
      wv1 = *(const uint4*)&W[(size_t)(row+128)*KD + k0 + seg*8];
      xv  = *(const uint4*)&Xb[(size_t)row*KD + k0 + seg*8];
    }
    bf16x8 af[4], bfr[4];
    #pragma unroll
    for (int to = 0; to < 4; ++to)
      af[to] = *(const bf16x8*)&Ws[(wo*64 + to*16 + l16)*32 + quad*8];
    #pragma unroll
    for (int tn = 0; tn < 4; ++tn)
      bfr[tn] = *(const bf16x8*)&Xs[(wn*64 + tn*16 + l16)*32 + quad*8];
    #pragma unroll
    for (int to = 0; to < 4; ++to)
      #pragma unroll
      for (int tn = 0; tn < 4; ++tn)
        acc[to][tn] = __builtin_amdgcn_mfma_f32_16x16x32_bf16(af[to], bfr[tn], acc[to][tn], 0, 0, 0);
  }

  // epilogue: bias, BN partial stats (shuffle-reduce over the 16 n-lanes)
  #pragma unroll
  for (int to = 0; to < 4; ++to) {
    #pragma unroll
    for (int r = 0; r < 4; ++r) {
      const int o = wo*64 + to*16 + quad*4 + r;
      const float bv = bias[o];
      float p = 0.f, q = 0.f;
      #pragma unroll
      for (int tn = 0; tn < 4; ++tn) {
        float v = acc[to][tn][r] + bv;
        acc[to][tn][r] = v;
        p += v; q = fmaf(v, v, q);
      }
      #pragma unroll
      for (int m = 1; m < 16; m <<= 1) { p += __shfl_xor(p, m); q += __shfl_xor(q, m); }
      if (l16 == 0) { atomicAdd(&bsum[o], p); atomicAdd(&bsq[o], q); }
    }
  }
  // store y^T bf16: [n][o], 8B per lane (L2 write-combines the 512B rows)
  #pragma unroll
  for (int to = 0; to < 4; ++to)
    #pragma unroll
    for (int tn = 0; tn < 4; ++tn) {
      const int n = n0 + wn*64 + tn*16 + l16;
      const int o = wo*64 + to*16 + quad*4;
      unsigned int lo = (unsigned)f2bf(acc[to][tn][0]) | ((unsigned)f2bf(acc[to][tn][1]) << 16);
      unsigned int hi = (unsigned)f2bf(acc[to][tn][2]) | ((unsigned)f2bf(acc[to][tn][3]) << 16);
      *(uint2*)&Y[((size_t)(b*NPTS + n))*256 + o] = make_uint2(lo, hi);
    }
}

// ---------------------------------------------------------------------------
// BN finalize
// ---------------------------------------------------------------------------
__global__ void bn_finalize_kernel(const float* __restrict__ s, const float* __restrict__ q,
                                   const float* __restrict__ g, const float* __restrict__ beta,
                                   float* __restrict__ scl, float* __restrict__ shf) {
  const int o = threadIdx.x;
  const float inv_n = 1.0f / NSAMP;
  const float mean = s[o] * inv_n;
  const float var  = q[o] * inv_n - mean*mean;
  const float sc = g[o] * rsqrtf(var + 1e-5f);
  scl[o] = sc;
  shf[o] = beta[o] - mean * sc;
}

// ---------------------------------------------------------------------------
// Final: y2t[b][n][o] bf16 -> out[b][o][n] fp32 with BN2+ReLU (tiled transpose)
// ---------------------------------------------------------------------------
__global__ __launch_bounds__(256)
void bn2_t_kernel(const unsigned short* __restrict__ Yt, const float* __restrict__ scl,
                  const float* __restrict__ shf, float* __restrict__ out) {
  __shared__ __align__(16) unsigned short T[64][72];
  const int tid = threadIdx.x;
  const int n0 = blockIdx.x*64, o0 = blockIdx.y*64, b = blockIdx.z;
  #pragma unroll
  for (int i = 0; i < 2; ++i) {
    int u = tid + i*256;
    int nl = u >> 3, o8 = (u & 7)*8;
    uint4 v = *(const uint4*)&Yt[((size_t)(b*NPTS + n0 + nl))*256 + o0 + o8];
    *(uint4*)&T[nl][o8] = v;
  }
  __syncthreads();
  #pragma unroll
  for (int i = 0; i < 4; ++i) {
    int u = tid + i*256;
    int ol = u >> 4, n4 = (u & 15)*4;
    const float s = scl[o0+ol], h = shf[o0+ol];
    float4 v;
    v.x = fmaxf(fmaf(bf2f(T[n4  ][ol]), s, h), 0.f);
    v.y = fmaxf(fmaf(bf2f(T[n4+1][ol]), s, h), 0.f);
    v.z = fmaxf(fmaf(bf2f(T[n4+2][ol]), s, h), 0.f);
    v.w = fmaxf(fmaf(bf2f(T[n4+3][ol]), s, h), 0.f);
    *(float4*)&out[((size_t)(b*256 + o0 + ol))*NPTS + n0 + n4] = v;
  }
}

// ---------------------------------------------------------------------------
// ws layout (bytes):
//   0        idx   int32[8*8192*3]          786432
//   786432   wgt   f32 [8*8192*3]           786432
//   1572864  bn    f32 [2048]                 8192  (sums x4, scl/shf x4)
//   1581056  w1b   bf16[256*512]            262144
//   1843200  w2b   bf16[256*256]            131072
//   2097152  X1t   bf16[8*8192*512]       67108864  (later reused as y2t)
// total 69206016 B (66 MB).  y1t lives in d_out (bf16, 32 MB of the 64).
// ---------------------------------------------------------------------------
extern "C" void kernel_launch(void* const* d_in, const int* in_sizes, int n_in,
                              void* d_out, int out_size, void* d_ws, size_t ws_size,
                              hipStream_t stream) {
  const float* xyz           = (const float*)d_in[0];
  const float* xyz_prev      = (const float*)d_in[1];
  const float* features      = (const float*)d_in[2];
  const float* features_prev = (const float*)d_in[3];
  const float* w1    = (const float*)d_in[4];
  const float* b1    = (const float*)d_in[5];
  const float* g1    = (const float*)d_in[6];
  const float* beta1 = (const float*)d_in[7];
  const float* w2    = (const float*)d_in[8];
  const float* b2    = (const float*)d_in[9];
  const float* g2    = (const float*)d_in[10];
  const float* beta2 = (const float*)d_in[11];
  float* out = (float*)d_out;

  char* ws = (char*)d_ws;
  int*            idxb = (int*)ws;
  float*          wgtb = (float*)(ws + 786432);
  float*          bn   = (float*)(ws + 1572864);
  unsigned short* w1b  = (unsigned short*)(ws + 1581056);
  unsigned short* w2b  = (unsigned short*)(ws + 1843200);
  unsigned short* X1t  = (unsigned short*)(ws + 2097152);
  unsigned short* y2t  = X1t;                      // X1t dead after GEMM1
  unsigned short* y1t  = (unsigned short*)d_out;   // scratch until final kernel

  float* bn1_sum = bn;        float* bn1_sq  = bn + 256;
  float* bn2_sum = bn + 512;  float* bn2_sq  = bn + 768;
  float* bn1_scl = bn + 1024; float* bn1_shf = bn + 1280;
  float* bn2_scl = bn + 1536; float* bn2_shf = bn + 1792;

  hipMemsetAsync(bn, 0, 4096, stream);

  cvt_kernel<<<512, 256, 0, stream>>>(w1, w1b, 131072);
  cvt_kernel<<<256, 256, 0, stream>>>(w2, w2b, 65536);

  three_nn_kernel<<<dim3(NPTS/256, BDIM), 256, 0, stream>>>(xyz, xyz_prev, idxb, wgtb);

  feat_t_kernel<<<dim3(NPTS/64, 4, BDIM), 256, 0, stream>>>(features, X1t);
  interp_t_kernel<<<dim3(NPTS/256, BDIM), 256, 0, stream>>>(features_prev, idxb, wgtb, X1t);

  gemm_t_kernel<512, 0><<<dim3(NPTS/128, BDIM), 512, 0, stream>>>(
      w1b, X1t, b1, nullptr, nullptr, y1t, bn1_sum, bn1_sq);
  bn_finalize_kernel<<<1, 256, 0, stream>>>(bn1_sum, bn1_sq, g1, beta1, bn1_scl, bn1_shf);

  gemm_t_kernel<256, 1><<<dim3(NPTS/128, BDIM), 512, 0, stream>>>(
      w2b, y1t, b2, bn1_scl, bn1_shf, y2t, bn2_sum, bn2_sq);
  bn_finalize_kernel<<<1, 256, 0, stream>>>(bn2_sum, bn2_sq, g2, beta2, bn2_scl, bn2_shf);

  bn2_t_kernel<<<dim3(NPTS/64, 4, BDIM), 256, 0, stream>>>(y2t, bn2_scl, bn2_shf, out);
}

// Round 3
// 733.388 us; speedup vs baseline: 1.1250x; 1.1250x over previous
//
#include <hip/hip_runtime.h>

#define BDIM 8
#define NPTS 8192
#define MPTS 2048
#define NSAMP 65536.0f
#define PITCH 40   // LDS row pitch in halves (80 B) -> 2-way max bank aliasing

typedef __attribute__((ext_vector_type(8))) short bf16x8;
typedef __attribute__((ext_vector_type(4))) float f32x4;

static __device__ __forceinline__ unsigned short f2bf(float f) {
  unsigned int x = __float_as_uint(f);
  x += 0x7FFFu + ((x >> 16) & 1u);          // round-to-nearest-even
  return (unsigned short)(x >> 16);
}
static __device__ __forceinline__ float bf2f(unsigned short u) {
  return __uint_as_float(((unsigned int)u) << 16);
}

// ---------------------------------------------------------------------------
// three_nn: exact reference fp32 formula, strict-< insertion (earlier idx wins)
// float4-packed LDS (broadcast b128 reads), unroll 16, batch-min skip branch.
// ---------------------------------------------------------------------------
__global__ __launch_bounds__(256)
void three_nn_kernel(const float* __restrict__ xyz, const float* __restrict__ xyz_prev,
                     int* __restrict__ idx_out, float* __restrict__ wgt_out) {
  __shared__ __align__(16) float4 pk[MPTS];
  const int b = blockIdx.y;
  const int tid = threadIdx.x;
  for (int j = tid; j < MPTS; j += 256) {
    float x = xyz_prev[((size_t)b*MPTS + j)*3 + 0];
    float y = xyz_prev[((size_t)b*MPTS + j)*3 + 1];
    float z = xyz_prev[((size_t)b*MPTS + j)*3 + 2];
    float s = __fadd_rn(__fadd_rn(__fmul_rn(x,x), __fmul_rn(y,y)), __fmul_rn(z,z));
    pk[j] = make_float4(x, y, z, s);
  }
  __syncthreads();
  const int n = blockIdx.x*256 + tid;
  const size_t qoff = ((size_t)b*NPTS + n)*3;
  const float qx = xyz[qoff], qy = xyz[qoff+1], qz = xyz[qoff+2];
  const float squ = __fadd_rn(__fadd_rn(__fmul_rn(qx,qx), __fmul_rn(qy,qy)), __fmul_rn(qz,qz));

  float d0 = 3.4e38f, d1 = 3.4e38f, d2v = 3.4e38f;
  int j0 = 0, j1 = 0, j2 = 0;
  for (int m = 0; m < MPTS; m += 16) {
    float dd[16];
    #pragma unroll
    for (int u = 0; u < 16; ++u) {
      const float4 p = pk[m + u];
      float dot = __fadd_rn(__fadd_rn(__fmul_rn(qx,p.x), __fmul_rn(qy,p.y)), __fmul_rn(qz,p.z));
      dd[u] = __fsub_rn(__fadd_rn(squ, p.w), __fmul_rn(2.0f, dot));
    }
    float mn = dd[0];
    #pragma unroll
    for (int u = 1; u < 16; ++u) mn = fminf(mn, dd[u]);
    if (mn < d2v) {                          // exec-mask skip for most batches
      #pragma unroll
      for (int u = 0; u < 16; ++u) {
        const float v = dd[u];
        if (v < d2v) {
          if (v < d1) {
            d2v = d1; j2 = j1;
            if (v < d0) { d1 = d0; j1 = j0; d0 = v; j0 = m + u; }
            else        { d1 = v;  j1 = m + u; }
          } else { d2v = v; j2 = m + u; }
        }
      }
    }
  }
  const float s0 = sqrtf(fmaxf(d0, 0.f));
  const float s1 = sqrtf(fmaxf(d1, 0.f));
  const float s2 = sqrtf(fmaxf(d2v, 0.f));
  const float i0 = 1.f/(s0 + 1e-8f), i1 = 1.f/(s1 + 1e-8f), i2 = 1.f/(s2 + 1e-8f);
  const float sum = i0 + i1 + i2;
  const size_t o = ((size_t)b*NPTS + n)*3;
  idx_out[o] = j0; idx_out[o+1] = j1; idx_out[o+2] = j2;
  wgt_out[o] = i0/sum; wgt_out[o+1] = i1/sum; wgt_out[o+2] = i2/sum;
}

// ---------------------------------------------------------------------------
// fp32 -> bf16 flat convert (for weights)
// ---------------------------------------------------------------------------
__global__ __launch_bounds__(256)
void cvt_kernel(const float* __restrict__ s, unsigned short* __restrict__ d, int n) {
  int t = blockIdx.x*256 + threadIdx.x;
  if (t < n) d[t] = f2bf(s[t]);
}

// ---------------------------------------------------------------------------
// features [b][c][n] fp32 -> X1t[b][n][256+c] bf16 (64x64 tiled transpose)
// ---------------------------------------------------------------------------
__global__ __launch_bounds__(256)
void feat_t_kernel(const float* __restrict__ feat, unsigned short* __restrict__ X1t) {
  __shared__ __align__(16) unsigned short St[64][72];
  const int tid = threadIdx.x;
  const int n0 = blockIdx.x*64, c0 = blockIdx.y*64, b = blockIdx.z;
  const int cl = tid >> 2;
  #pragma unroll
  for (int i = 0; i < 4; ++i) {
    int nl = (tid & 3)*16 + i*4;
    float4 v = *(const float4*)&feat[((size_t)(b*256 + c0 + cl))*NPTS + n0 + nl];
    St[cl][nl]   = f2bf(v.x); St[cl][nl+1] = f2bf(v.y);
    St[cl][nl+2] = f2bf(v.z); St[cl][nl+3] = f2bf(v.w);
  }
  __syncthreads();
  #pragma unroll
  for (int i = 0; i < 2; ++i) {
    int u = tid + i*256;
    int nl = u >> 3, c8 = (u & 7)*8;
    unsigned short tmp[8];
    #pragma unroll
    for (int j = 0; j < 8; ++j) tmp[j] = St[c8 + j][nl];
    *(uint4*)&X1t[((size_t)(b*NPTS + n0 + nl))*512 + 256 + c0 + c8] = *(uint4*)tmp;
  }
}

// ---------------------------------------------------------------------------
// interpolate -> X1t[b][n][c] bf16 (c in [0,256))
// ---------------------------------------------------------------------------
__global__ __launch_bounds__(256)
void interp_t_kernel(const float* __restrict__ fp, const int* __restrict__ idx,
                     const float* __restrict__ wgt, unsigned short* __restrict__ X1t) {
  const int tid = threadIdx.x;
  const int b = blockIdx.y, n = blockIdx.x*256 + tid;
  const size_t p = ((size_t)b*NPTS + n)*3;
  const int i0 = idx[p], i1 = idx[p+1], i2 = idx[p+2];
  const float w0 = wgt[p], w1 = wgt[p+1], w2 = wgt[p+2];
  const float* fb = fp + (size_t)b*256*MPTS;
  unsigned short* dst = X1t + ((size_t)b*NPTS + n)*512;
  for (int c8 = 0; c8 < 256; c8 += 8) {
    unsigned short tmp[8];
    #pragma unroll
    for (int j = 0; j < 8; ++j) {
      const float* frow = fb + (size_t)(c8 + j)*MPTS;
      tmp[j] = f2bf(frow[i0]*w0 + frow[i1]*w1 + frow[i2]*w2);
    }
    *(uint4*)&dst[c8] = *(uint4*)tmp;
  }
}

// ---------------------------------------------------------------------------
// MFMA GEMM: Y[b][n][o] = sum_k W[o][k] * Xt[b][n][k]  (all bf16, fp32 acc)
// 512 thr (8 waves = 4 o-groups x 2 n-groups), tile [256 o][128 n], BK=32,
// LDS rows padded to PITCH=40 halves (2-way max bank aliasing).
// MODE 1: fused BN1+ReLU on X during staging. Epilogue: +bias, BN stats.
// ---------------------------------------------------------------------------
template<int KD, int MODE>
__global__ __launch_bounds__(512)
void gemm_t_kernel(const unsigned short* __restrict__ W, const unsigned short* __restrict__ X,
                   const float* __restrict__ bias, const float* __restrict__ scl,
                   const float* __restrict__ shf, unsigned short* __restrict__ Y,
                   float* __restrict__ bsum, float* __restrict__ bsq) {
  __shared__ __align__(16) unsigned short Ws[256*PITCH];
  __shared__ __align__(16) unsigned short Xs[128*PITCH];
  const int tid = threadIdx.x;
  const int b = blockIdx.y, n0 = blockIdx.x*128;
  const int row = tid >> 2, seg = tid & 3;          // 128 rows x 4 16B-segments
  const unsigned short* Xb = X + (size_t)(b*NPTS + n0)*KD;

  uint4 wv0 = *(const uint4*)&W[(size_t)row*KD + seg*8];
  uint4 wv1 = *(const uint4*)&W[(size_t)(row+128)*KD + seg*8];
  uint4 xv  = *(const uint4*)&Xb[(size_t)row*KD + seg*8];

  f32x4 acc[4][4];
  #pragma unroll
  for (int i = 0; i < 4; ++i)
    #pragma unroll
    for (int j = 0; j < 4; ++j) acc[i][j] = (f32x4){0.f,0.f,0.f,0.f};

  const int lane = tid & 63, l16 = lane & 15, quad = lane >> 4;
  const int wave = tid >> 6, wo = wave >> 1, wn = wave & 1;

  for (int kt = 0; kt < KD/32; ++kt) {
    __syncthreads();
    *(uint4*)&Ws[row*PITCH + seg*8]       = wv0;
    *(uint4*)&Ws[(row+128)*PITCH + seg*8] = wv1;
    if (MODE == 0) {
      *(uint4*)&Xs[row*PITCH + seg*8] = xv;
    } else {
      const int kc = kt*32 + seg*8;
      float4 s0 = *(const float4*)&scl[kc], s1 = *(const float4*)&scl[kc+4];
      float4 h0 = *(const float4*)&shf[kc], h1 = *(const float4*)&shf[kc+4];
      const unsigned short* xu = (const unsigned short*)&xv;
      unsigned short t[8];
      t[0] = f2bf(fmaxf(fmaf(bf2f(xu[0]), s0.x, h0.x), 0.f));
      t[1] = f2bf(fmaxf(fmaf(bf2f(xu[1]), s0.y, h0.y), 0.f));
      t[2] = f2bf(fmaxf(fmaf(bf2f(xu[2]), s0.z, h0.z), 0.f));
      t[3] = f2bf(fmaxf(fmaf(bf2f(xu[3]), s0.w, h0.w), 0.f));
      t[4] = f2bf(fmaxf(fmaf(bf2f(xu[4]), s1.x, h1.x), 0.f));
      t[5] = f2bf(fmaxf(fmaf(bf2f(xu[5]), s1.y, h1.y), 0.f));
      t[6] = f2bf(fmaxf(fmaf(bf2f(xu[6]), s1.z, h1.z), 0.f));
      t[7] = f2bf(fmaxf(fmaf(bf2f(xu[7]), s1.w, h1.w), 0.f));
      *(uint4*)&Xs[row*PITCH + seg*8] = *(uint4*)t;
    }
    __syncthreads();
    if (kt + 1 < KD/32) {
      const int k0 = (kt+1)*32;
      wv0 = *(const uint4*)&W[(size_t)row*KD + k0 + seg*8];
      wv1 = *(const uint4*)&W[(size_t)(row+128)*KD + k0 + seg*8];
      xv  = *(const uint4*)&Xb[(size_t)row*KD + k0 + seg*8];
    }
    bf16x8 af[4], bfr[4];
    #pragma unroll
    for (int to = 0; to < 4; ++to)
      af[to] = *(const bf16x8*)&Ws[(wo*64 + to*16 + l16)*PITCH + quad*8];
    #pragma unroll
    for (int tn = 0; tn < 4; ++tn)
      bfr[tn] = *(const bf16x8*)&Xs[(wn*64 + tn*16 + l16)*PITCH + quad*8];
    #pragma unroll
    for (int to = 0; to < 4; ++to)
      #pragma unroll
      for (int tn = 0; tn < 4; ++tn)
        acc[to][tn] = __builtin_amdgcn_mfma_f32_16x16x32_bf16(af[to], bfr[tn], acc[to][tn], 0, 0, 0);
  }

  // epilogue: bias, BN partial stats (shuffle-reduce over the 16 n-lanes)
  #pragma unroll
  for (int to = 0; to < 4; ++to) {
    #pragma unroll
    for (int r = 0; r < 4; ++r) {
      const int o = wo*64 + to*16 + quad*4 + r;
      const float bv = bias[o];
      float p = 0.f, q = 0.f;
      #pragma unroll
      for (int tn = 0; tn < 4; ++tn) {
        float v = acc[to][tn][r] + bv;
        acc[to][tn][r] = v;
        p += v; q = fmaf(v, v, q);
      }
      #pragma unroll
      for (int m = 1; m < 16; m <<= 1) { p += __shfl_xor(p, m); q += __shfl_xor(q, m); }
      if (l16 == 0) { atomicAdd(&bsum[o], p); atomicAdd(&bsq[o], q); }
    }
  }
  // store y^T bf16: [n][o], 8B per lane
  #pragma unroll
  for (int to = 0; to < 4; ++to)
    #pragma unroll
    for (int tn = 0; tn < 4; ++tn) {
      const int n = n0 + wn*64 + tn*16 + l16;
      const int o = wo*64 + to*16 + quad*4;
      unsigned int lo = (unsigned)f2bf(acc[to][tn][0]) | ((unsigned)f2bf(acc[to][tn][1]) << 16);
      unsigned int hi = (unsigned)f2bf(acc[to][tn][2]) | ((unsigned)f2bf(acc[to][tn][3]) << 16);
      *(uint2*)&Y[((size_t)(b*NPTS + n))*256 + o] = make_uint2(lo, hi);
    }
}

// ---------------------------------------------------------------------------
// BN finalize
// ---------------------------------------------------------------------------
__global__ void bn_finalize_kernel(const float* __restrict__ s, const float* __restrict__ q,
                                   const float* __restrict__ g, const float* __restrict__ beta,
                                   float* __restrict__ scl, float* __restrict__ shf) {
  const int o = threadIdx.x;
  const float inv_n = 1.0f / NSAMP;
  const float mean = s[o] * inv_n;
  const float var  = q[o] * inv_n - mean*mean;
  const float sc = g[o] * rsqrtf(var + 1e-5f);
  scl[o] = sc;
  shf[o] = beta[o] - mean * sc;
}

// ---------------------------------------------------------------------------
// Final: y2t[b][n][o] bf16 -> out[b][o][n] fp32 with BN2+ReLU (tiled transpose)
// ---------------------------------------------------------------------------
__global__ __launch_bounds__(256)
void bn2_t_kernel(const unsigned short* __restrict__ Yt, const float* __restrict__ scl,
                  const float* __restrict__ shf, float* __restrict__ out) {
  __shared__ __align__(16) unsigned short T[64][72];
  const int tid = threadIdx.x;
  const int n0 = blockIdx.x*64, o0 = blockIdx.y*64, b = blockIdx.z;
  #pragma unroll
  for (int i = 0; i < 2; ++i) {
    int u = tid + i*256;
    int nl = u >> 3, o8 = (u & 7)*8;
    uint4 v = *(const uint4*)&Yt[((size_t)(b*NPTS + n0 + nl))*256 + o0 + o8];
    *(uint4*)&T[nl][o8] = v;
  }
  __syncthreads();
  #pragma unroll
  for (int i = 0; i < 4; ++i) {
    int u = tid + i*256;
    int ol = u >> 4, n4 = (u & 15)*4;
    const float s = scl[o0+ol], h = shf[o0+ol];
    float4 v;
    v.x = fmaxf(fmaf(bf2f(T[n4  ][ol]), s, h), 0.f);
    v.y = fmaxf(fmaf(bf2f(T[n4+1][ol]), s, h), 0.f);
    v.z = fmaxf(fmaf(bf2f(T[n4+2][ol]), s, h), 0.f);
    v.w = fmaxf(fmaf(bf2f(T[n4+3][ol]), s, h), 0.f);
    *(float4*)&out[((size_t)(b*256 + o0 + ol))*NPTS + n0 + n4] = v;
  }
}

// ---------------------------------------------------------------------------
// ws layout unchanged from R2.
// ---------------------------------------------------------------------------
extern "C" void kernel_launch(void* const* d_in, const int* in_sizes, int n_in,
                              void* d_out, int out_size, void* d_ws, size_t ws_size,
                              hipStream_t stream) {
  const float* xyz           = (const float*)d_in[0];
  const float* xyz_prev      = (const float*)d_in[1];
  const float* features      = (const float*)d_in[2];
  const float* features_prev = (const float*)d_in[3];
  const float* w1    = (const float*)d_in[4];
  const float* b1    = (const float*)d_in[5];
  const float* g1    = (const float*)d_in[6];
  const float* beta1 = (const float*)d_in[7];
  const float* w2    = (const float*)d_in[8];
  const float* b2    = (const float*)d_in[9];
  const float* g2    = (const float*)d_in[10];
  const float* beta2 = (const float*)d_in[11];
  float* out = (float*)d_out;

  char* ws = (char*)d_ws;
  int*            idxb = (int*)ws;
  float*          wgtb = (float*)(ws + 786432);
  float*          bn   = (float*)(ws + 1572864);
  unsigned short* w1b  = (unsigned short*)(ws + 1581056);
  unsigned short* w2b  = (unsigned short*)(ws + 1843200);
  unsigned short* X1t  = (unsigned short*)(ws + 2097152);
  unsigned short* y2t  = X1t;                      // X1t dead after GEMM1
  unsigned short* y1t  = (unsigned short*)d_out;   // scratch until final kernel

  float* bn1_sum = bn;        float* bn1_sq  = bn + 256;
  float* bn2_sum = bn + 512;  float* bn2_sq  = bn + 768;
  float* bn1_scl = bn + 1024; float* bn1_shf = bn + 1280;
  float* bn2_scl = bn + 1536; float* bn2_shf = bn + 1792;

  hipMemsetAsync(bn, 0, 4096, stream);

  cvt_kernel<<<512, 256, 0, stream>>>(w1, w1b, 131072);
  cvt_kernel<<<256, 256, 0, stream>>>(w2, w2b, 65536);

  three_nn_kernel<<<dim3(NPTS/256, BDIM), 256, 0, stream>>>(xyz, xyz_prev, idxb, wgtb);

  feat_t_kernel<<<dim3(NPTS/64, 4, BDIM), 256, 0, stream>>>(features, X1t);
  interp_t_kernel<<<dim3(NPTS/256, BDIM), 256, 0, stream>>>(features_prev, idxb, wgtb, X1t);

  gemm_t_kernel<512, 0><<<dim3(NPTS/128, BDIM), 512, 0, stream>>>(
      w1b, X1t, b1, nullptr, nullptr, y1t, bn1_sum, bn1_sq);
  bn_finalize_kernel<<<1, 256, 0, stream>>>(bn1_sum, bn1_sq, g1, beta1, bn1_scl, bn1_shf);

  gemm_t_kernel<256, 1><<<dim3(NPTS/128, BDIM), 512, 0, stream>>>(
      w2b, y1t, b2, bn1_scl, bn1_shf, y2t, bn2_sum, bn2_sq);
  bn_finalize_kernel<<<1, 256, 0, stream>>>(bn2_sum, bn2_sq, g2, beta2, bn2_scl, bn2_shf);

  bn2_t_kernel<<<dim3(NPTS/64, 4, BDIM), 256, 0, stream>>>(y2t, bn2_scl, bn2_shf, out);
}

// Round 4
// 594.026 us; speedup vs baseline: 1.3889x; 1.2346x over previous
//
#include <hip/hip_runtime.h>

#define BDIM 8
#define NPTS 8192
#define MPTS 2048
#define NSAMP 65536.0f
#define PITCH 40   // GEMM LDS row pitch in halves (80 B) -> 2-way max bank aliasing

typedef __attribute__((ext_vector_type(8))) short bf16x8;
typedef __attribute__((ext_vector_type(4))) float f32x4;

static __device__ __forceinline__ unsigned short f2bf(float f) {
  unsigned int x = __float_as_uint(f);
  x += 0x7FFFu + ((x >> 16) & 1u);          // round-to-nearest-even
  return (unsigned short)(x >> 16);
}
static __device__ __forceinline__ float bf2f(unsigned short u) {
  return __uint_as_float(((unsigned int)u) << 16);
}

// ---------------------------------------------------------------------------
// three_nn: exact reference fp32 formula, strict-< insertion (earlier idx wins)
// ---------------------------------------------------------------------------
__global__ __launch_bounds__(256)
void three_nn_kernel(const float* __restrict__ xyz, const float* __restrict__ xyz_prev,
                     int* __restrict__ idx_out, float* __restrict__ wgt_out) {
  __shared__ __align__(16) float4 pk[MPTS];
  const int b = blockIdx.y;
  const int tid = threadIdx.x;
  for (int j = tid; j < MPTS; j += 256) {
    float x = xyz_prev[((size_t)b*MPTS + j)*3 + 0];
    float y = xyz_prev[((size_t)b*MPTS + j)*3 + 1];
    float z = xyz_prev[((size_t)b*MPTS + j)*3 + 2];
    float s = __fadd_rn(__fadd_rn(__fmul_rn(x,x), __fmul_rn(y,y)), __fmul_rn(z,z));
    pk[j] = make_float4(x, y, z, s);
  }
  __syncthreads();
  const int n = blockIdx.x*256 + tid;
  const size_t qoff = ((size_t)b*NPTS + n)*3;
  const float qx = xyz[qoff], qy = xyz[qoff+1], qz = xyz[qoff+2];
  const float squ = __fadd_rn(__fadd_rn(__fmul_rn(qx,qx), __fmul_rn(qy,qy)), __fmul_rn(qz,qz));

  float d0 = 3.4e38f, d1 = 3.4e38f, d2v = 3.4e38f;
  int j0 = 0, j1 = 0, j2 = 0;
  for (int m = 0; m < MPTS; m += 16) {
    float dd[16];
    #pragma unroll
    for (int u = 0; u < 16; ++u) {
      const float4 p = pk[m + u];
      float dot = __fadd_rn(__fadd_rn(__fmul_rn(qx,p.x), __fmul_rn(qy,p.y)), __fmul_rn(qz,p.z));
      dd[u] = __fsub_rn(__fadd_rn(squ, p.w), __fmul_rn(2.0f, dot));
    }
    float mn = dd[0];
    #pragma unroll
    for (int u = 1; u < 16; ++u) mn = fminf(mn, dd[u]);
    if (mn < d2v) {                          // exec-mask skip for most batches
      #pragma unroll
      for (int u = 0; u < 16; ++u) {
        const float v = dd[u];
        if (v < d2v) {
          if (v < d1) {
            d2v = d1; j2 = j1;
            if (v < d0) { d1 = d0; j1 = j0; d0 = v; j0 = m + u; }
            else        { d1 = v;  j1 = m + u; }
          } else { d2v = v; j2 = m + u; }
        }
      }
    }
  }
  const float s0 = sqrtf(fmaxf(d0, 0.f));
  const float s1 = sqrtf(fmaxf(d1, 0.f));
  const float s2 = sqrtf(fmaxf(d2v, 0.f));
  const float i0 = 1.f/(s0 + 1e-8f), i1 = 1.f/(s1 + 1e-8f), i2 = 1.f/(s2 + 1e-8f);
  const float sum = i0 + i1 + i2;
  const size_t o = ((size_t)b*NPTS + n)*3;
  idx_out[o] = j0; idx_out[o+1] = j1; idx_out[o+2] = j2;
  wgt_out[o] = i0/sum; wgt_out[o+1] = i1/sum; wgt_out[o+2] = i2/sum;
}

// ---------------------------------------------------------------------------
// fp32 -> bf16 flat convert (for weights)
// ---------------------------------------------------------------------------
__global__ __launch_bounds__(256)
void cvt_kernel(const float* __restrict__ s, unsigned short* __restrict__ d, int n) {
  int t = blockIdx.x*256 + threadIdx.x;
  if (t < n) d[t] = f2bf(s[t]);
}

// ---------------------------------------------------------------------------
// Generic [b][c][SRCW] fp32 -> dst[b][n][DOFF + c] bf16 tiled transpose.
//   feat:          SRCW=8192, DPITCH=512, DOFF=256  (features -> X1t upper)
//   features_prev: SRCW=2048, DPITCH=256, DOFF=0    (-> fpT rows)
// ---------------------------------------------------------------------------
template<int SRCW, int DPITCH, int DOFF>
__global__ __launch_bounds__(256)
void trans_bf16_kernel(const float* __restrict__ src, unsigned short* __restrict__ dst) {
  __shared__ __align__(16) unsigned short St[64][72];
  const int tid = threadIdx.x;
  const int n0 = blockIdx.x*64, c0 = blockIdx.y*64, b = blockIdx.z;
  const int cl = tid >> 2;
  #pragma unroll
  for (int i = 0; i < 4; ++i) {
    int nl = (tid & 3)*16 + i*4;
    float4 v = *(const float4*)&src[((size_t)(b*256 + c0 + cl))*SRCW + n0 + nl];
    St[cl][nl]   = f2bf(v.x); St[cl][nl+1] = f2bf(v.y);
    St[cl][nl+2] = f2bf(v.z); St[cl][nl+3] = f2bf(v.w);
  }
  __syncthreads();
  #pragma unroll
  for (int i = 0; i < 2; ++i) {
    int u = tid + i*256;
    int nl = u >> 3, c8 = (u & 7)*8;
    unsigned short tmp[8];
    #pragma unroll
    for (int j = 0; j < 8; ++j) tmp[j] = St[c8 + j][nl];
    *(uint4*)&dst[((size_t)(b*SRCW + n0 + nl))*DPITCH + DOFF + c0 + c8] = *(uint4*)tmp;
  }
}

// ---------------------------------------------------------------------------
// interpolate from row-major fpT[b][m][256] bf16 -> X1t[b][n][0:256] bf16.
// 32 lanes per query point: each gather is a 512 B contiguous row read.
// ---------------------------------------------------------------------------
__global__ __launch_bounds__(256)
void interp_t_kernel(const unsigned short* __restrict__ fpT, const int* __restrict__ idx,
                     const float* __restrict__ wgt, unsigned short* __restrict__ X1t) {
  const int tid = threadIdx.x;
  const int b = blockIdx.y;
  const int n = blockIdx.x*8 + (tid >> 5);      // 8 points per block
  const int c8 = (tid & 31)*8;                  // this lane's 8-channel slice
  const size_t p = ((size_t)b*NPTS + n)*3;
  const int i0 = idx[p], i1 = idx[p+1], i2 = idx[p+2];
  const float w0 = wgt[p], w1 = wgt[p+1], w2 = wgt[p+2];
  const unsigned short* fb = fpT + (size_t)b*MPTS*256 + c8;
  uint4 a0 = *(const uint4*)&fb[(size_t)i0*256];
  uint4 a1 = *(const uint4*)&fb[(size_t)i1*256];
  uint4 a2 = *(const uint4*)&fb[(size_t)i2*256];
  const unsigned short* u0 = (const unsigned short*)&a0;
  const unsigned short* u1 = (const unsigned short*)&a1;
  const unsigned short* u2 = (const unsigned short*)&a2;
  unsigned short r[8];
  #pragma unroll
  for (int j = 0; j < 8; ++j) {
    float v = bf2f(u0[j])*w0 + bf2f(u1[j])*w1 + bf2f(u2[j])*w2;
    r[j] = f2bf(v);
  }
  *(uint4*)&X1t[((size_t)b*NPTS + n)*512 + c8] = *(uint4*)r;
}

// ---------------------------------------------------------------------------
// MFMA GEMM: Y[b][n][o] = sum_k W[o][k] * Xt[b][n][k]  (all bf16, fp32 acc)
// 512 thr (8 waves = 4 o-groups x 2 n-groups), tile [256 o][128 n], BK=32,
// LDS rows padded to PITCH=40 halves (2-way max bank aliasing).
// MODE 1: fused BN1+ReLU on X during staging. Epilogue: +bias, BN stats.
// ---------------------------------------------------------------------------
template<int KD, int MODE>
__global__ __launch_bounds__(512)
void gemm_t_kernel(const unsigned short* __restrict__ W, const unsigned short* __restrict__ X,
                   const float* __restrict__ bias, const float* __restrict__ scl,
                   const float* __restrict__ shf, unsigned short* __restrict__ Y,
                   float* __restrict__ bsum, float* __restrict__ bsq) {
  __shared__ __align__(16) unsigned short Ws[256*PITCH];
  __shared__ __align__(16) unsigned short Xs[128*PITCH];
  const int tid = threadIdx.x;
  const int b = blockIdx.y, n0 = blockIdx.x*128;
  const int row = tid >> 2, seg = tid & 3;          // 128 rows x 4 16B-segments
  const unsigned short* Xb = X + (size_t)(b*NPTS + n0)*KD;

  uint4 wv0 = *(const uint4*)&W[(size_t)row*KD + seg*8];
  uint4 wv1 = *(const uint4*)&W[(size_t)(row+128)*KD + seg*8];
  uint4 xv  = *(const uint4*)&Xb[(size_t)row*KD + seg*8];

  f32x4 acc[4][4];
  #pragma unroll
  for (int i = 0; i < 4; ++i)
    #pragma unroll
    for (int j = 0; j < 4; ++j) acc[i][j] = (f32x4){0.f,0.f,0.f,0.f};

  const int lane = tid & 63, l16 = lane & 15, quad = lane >> 4;
  const int wave = tid >> 6, wo = wave >> 1, wn = wave & 1;

  for (int kt = 0; kt < KD/32; ++kt) {
    __syncthreads();
    *(uint4*)&Ws[row*PITCH + seg*8]       = wv0;
    *(uint4*)&Ws[(row+128)*PITCH + seg*8] = wv1;
    if (MODE == 0) {
      *(uint4*)&Xs[row*PITCH + seg*8] = xv;
    } else {
      const int kc = kt*32 + seg*8;
      float4 s0 = *(const float4*)&scl[kc], s1 = *(const float4*)&scl[kc+4];
      float4 h0 = *(const float4*)&shf[kc], h1 = *(const float4*)&shf[kc+4];
      const unsigned short* xu = (const unsigned short*)&xv;
      unsigned short t[8];
      t[0] = f2bf(fmaxf(fmaf(bf2f(xu[0]), s0.x, h0.x), 0.f));
      t[1] = f2bf(fmaxf(fmaf(bf2f(xu[1]), s0.y, h0.y), 0.f));
      t[2] = f2bf(fmaxf(fmaf(bf2f(xu[2]), s0.z, h0.z), 0.f));
      t[3] = f2bf(fmaxf(fmaf(bf2f(xu[3]), s0.w, h0.w), 0.f));
      t[4] = f2bf(fmaxf(fmaf(bf2f(xu[4]), s1.x, h1.x), 0.f));
      t[5] = f2bf(fmaxf(fmaf(bf2f(xu[5]), s1.y, h1.y), 0.f));
      t[6] = f2bf(fmaxf(fmaf(bf2f(xu[6]), s1.z, h1.z), 0.f));
      t[7] = f2bf(fmaxf(fmaf(bf2f(xu[7]), s1.w, h1.w), 0.f));
      *(uint4*)&Xs[row*PITCH + seg*8] = *(uint4*)t;
    }
    __syncthreads();
    if (kt + 1 < KD/32) {
      const int k0 = (kt+1)*32;
      wv0 = *(const uint4*)&W[(size_t)row*KD + k0 + seg*8];
      wv1 = *(const uint4*)&W[(size_t)(row+128)*KD + k0 + seg*8];
      xv  = *(const uint4*)&Xb[(size_t)row*KD + k0 + seg*8];
    }
    bf16x8 af[4], bfr[4];
    #pragma unroll
    for (int to = 0; to < 4; ++to)
      af[to] = *(const bf16x8*)&Ws[(wo*64 + to*16 + l16)*PITCH + quad*8];
    #pragma unroll
    for (int tn = 0; tn < 4; ++tn)
      bfr[tn] = *(const bf16x8*)&Xs[(wn*64 + tn*16 + l16)*PITCH + quad*8];
    #pragma unroll
    for (int to = 0; to < 4; ++to)
      #pragma unroll
      for (int tn = 0; tn < 4; ++tn)
        acc[to][tn] = __builtin_amdgcn_mfma_f32_16x16x32_bf16(af[to], bfr[tn], acc[to][tn], 0, 0, 0);
  }

  // epilogue: bias, BN partial stats (shuffle-reduce over the 16 n-lanes)
  #pragma unroll
  for (int to = 0; to < 4; ++to) {
    #pragma unroll
    for (int r = 0; r < 4; ++r) {
      const int o = wo*64 + to*16 + quad*4 + r;
      const float bv = bias[o];
      float p = 0.f, q = 0.f;
      #pragma unroll
      for (int tn = 0; tn < 4; ++tn) {
        float v = acc[to][tn][r] + bv;
        acc[to][tn][r] = v;
        p += v; q = fmaf(v, v, q);
      }
      #pragma unroll
      for (int m = 1; m < 16; m <<= 1) { p += __shfl_xor(p, m); q += __shfl_xor(q, m); }
      if (l16 == 0) { atomicAdd(&bsum[o], p); atomicAdd(&bsq[o], q); }
    }
  }
  // store y^T bf16: [n][o], 8B per lane
  #pragma unroll
  for (int to = 0; to < 4; ++to)
    #pragma unroll
    for (int tn = 0; tn < 4; ++tn) {
      const int n = n0 + wn*64 + tn*16 + l16;
      const int o = wo*64 + to*16 + quad*4;
      unsigned int lo = (unsigned)f2bf(acc[to][tn][0]) | ((unsigned)f2bf(acc[to][tn][1]) << 16);
      unsigned int hi = (unsigned)f2bf(acc[to][tn][2]) | ((unsigned)f2bf(acc[to][tn][3]) << 16);
      *(uint2*)&Y[((size_t)(b*NPTS + n))*256 + o] = make_uint2(lo, hi);
    }
}

// ---------------------------------------------------------------------------
// BN finalize
// ---------------------------------------------------------------------------
__global__ void bn_finalize_kernel(const float* __restrict__ s, const float* __restrict__ q,
                                   const float* __restrict__ g, const float* __restrict__ beta,
                                   float* __restrict__ scl, float* __restrict__ shf) {
  const int o = threadIdx.x;
  const float inv_n = 1.0f / NSAMP;
  const float mean = s[o] * inv_n;
  const float var  = q[o] * inv_n - mean*mean;
  const float sc = g[o] * rsqrtf(var + 1e-5f);
  scl[o] = sc;
  shf[o] = beta[o] - mean * sc;
}

// ---------------------------------------------------------------------------
// Final: y2t[b][n][o] bf16 -> out[b][o][n] fp32 with BN2+ReLU (tiled transpose)
// ---------------------------------------------------------------------------
__global__ __launch_bounds__(256)
void bn2_t_kernel(const unsigned short* __restrict__ Yt, const float* __restrict__ scl,
                  const float* __restrict__ shf, float* __restrict__ out) {
  __shared__ __align__(16) unsigned short T[64][72];
  const int tid = threadIdx.x;
  const int n0 = blockIdx.x*64, o0 = blockIdx.y*64, b = blockIdx.z;
  #pragma unroll
  for (int i = 0; i < 2; ++i) {
    int u = tid + i*256;
    int nl = u >> 3, o8 = (u & 7)*8;
    uint4 v = *(const uint4*)&Yt[((size_t)(b*NPTS + n0 + nl))*256 + o0 + o8];
    *(uint4*)&T[nl][o8] = v;
  }
  __syncthreads();
  #pragma unroll
  for (int i = 0; i < 4; ++i) {
    int u = tid + i*256;
    int ol = u >> 4, n4 = (u & 15)*4;
    const float s = scl[o0+ol], h = shf[o0+ol];
    float4 v;
    v.x = fmaxf(fmaf(bf2f(T[n4  ][ol]), s, h), 0.f);
    v.y = fmaxf(fmaf(bf2f(T[n4+1][ol]), s, h), 0.f);
    v.z = fmaxf(fmaf(bf2f(T[n4+2][ol]), s, h), 0.f);
    v.w = fmaxf(fmaf(bf2f(T[n4+3][ol]), s, h), 0.f);
    *(float4*)&out[((size_t)(b*256 + o0 + ol))*NPTS + n0 + n4] = v;
  }
}

// ---------------------------------------------------------------------------
// ws layout (bytes):
//   0        idx   int32[8*8192*3]          786432
//   786432   wgt   f32 [8*8192*3]           786432
//   1572864  bn    f32 [2048]                 8192
//   1581056  w1b   bf16[256*512]            262144
//   1843200  w2b   bf16[256*256]            131072
//   2097152  X1t   bf16[8*8192*512]       67108864  (later reused as y2t)
// d_out (64 MB f32 out buffer) doubles as scratch:
//   [0,32MB)   y1t bf16[8*8192*256]
//   [32,40MB)  fpT bf16[8*2048*256]  (features_prev row-major, gather source)
// ---------------------------------------------------------------------------
extern "C" void kernel_launch(void* const* d_in, const int* in_sizes, int n_in,
                              void* d_out, int out_size, void* d_ws, size_t ws_size,
                              hipStream_t stream) {
  const float* xyz           = (const float*)d_in[0];
  const float* xyz_prev      = (const float*)d_in[1];
  const float* features      = (const float*)d_in[2];
  const float* features_prev = (const float*)d_in[3];
  const float* w1    = (const float*)d_in[4];
  const float* b1    = (const float*)d_in[5];
  const float* g1    = (const float*)d_in[6];
  const float* beta1 = (const float*)d_in[7];
  const float* w2    = (const float*)d_in[8];
  const float* b2    = (const float*)d_in[9];
  const float* g2    = (const float*)d_in[10];
  const float* beta2 = (const float*)d_in[11];
  float* out = (float*)d_out;

  char* ws = (char*)d_ws;
  int*            idxb = (int*)ws;
  float*          wgtb = (float*)(ws + 786432);
  float*          bn   = (float*)(ws + 1572864);
  unsigned short* w1b  = (unsigned short*)(ws + 1581056);
  unsigned short* w2b  = (unsigned short*)(ws + 1843200);
  unsigned short* X1t  = (unsigned short*)(ws + 2097152);
  unsigned short* y2t  = X1t;                      // X1t dead after GEMM1
  unsigned short* y1t  = (unsigned short*)d_out;   // scratch until final kernel
  unsigned short* fpT  = (unsigned short*)((char*)d_out + 33554432);

  float* bn1_sum = bn;        float* bn1_sq  = bn + 256;
  float* bn2_sum = bn + 512;  float* bn2_sq  = bn + 768;
  float* bn1_scl = bn + 1024; float* bn1_shf = bn + 1280;
  float* bn2_scl = bn + 1536; float* bn2_shf = bn + 1792;

  hipMemsetAsync(bn, 0, 4096, stream);

  cvt_kernel<<<512, 256, 0, stream>>>(w1, w1b, 131072);
  cvt_kernel<<<256, 256, 0, stream>>>(w2, w2b, 65536);

  three_nn_kernel<<<dim3(NPTS/256, BDIM), 256, 0, stream>>>(xyz, xyz_prev, idxb, wgtb);

  // features -> X1t[:, :, 256:512]
  trans_bf16_kernel<NPTS, 512, 256><<<dim3(NPTS/64, 4, BDIM), 256, 0, stream>>>(features, X1t);
  // features_prev -> fpT row-major
  trans_bf16_kernel<MPTS, 256, 0><<<dim3(MPTS/64, 4, BDIM), 256, 0, stream>>>(features_prev, fpT);

  interp_t_kernel<<<dim3(NPTS/8, BDIM), 256, 0, stream>>>(fpT, idxb, wgtb, X1t);

  gemm_t_kernel<512, 0><<<dim3(NPTS/128, BDIM), 512, 0, stream>>>(
      w1b, X1t, b1, nullptr, nullptr, y1t, bn1_sum, bn1_sq);
  bn_finalize_kernel<<<1, 256, 0, stream>>>(bn1_sum, bn1_sq, g1, beta1, bn1_scl, bn1_shf);

  gemm_t_kernel<256, 1><<<dim3(NPTS/128, BDIM), 512, 0, stream>>>(
      w2b, y1t, b2, bn1_scl, bn1_shf, y2t, bn2_sum, bn2_sq);
  bn_finalize_kernel<<<1, 256, 0, stream>>>(bn2_sum, bn2_sq, g2, beta2, bn2_scl, bn2_shf);

  bn2_t_kernel<<<dim3(NPTS/64, 4, BDIM), 256, 0, stream>>>(y2t, bn2_scl, bn2_shf, out);
}

// Round 5
// 444.433 us; speedup vs baseline: 1.8564x; 1.3366x over previous
//
#include <hip/hip_runtime.h>

#define BDIM 8
#define NPTS 8192
#define MPTS 2048
#define NSAMP 65536.0f
#define PITCH 40   // GEMM LDS row pitch in halves (80 B) -> 2-way max bank aliasing

typedef __attribute__((ext_vector_type(8))) short bf16x8;
typedef __attribute__((ext_vector_type(4))) float f32x4;

static __device__ __forceinline__ unsigned short f2bf(float f) {
  unsigned int x = __float_as_uint(f);
  x += 0x7FFFu + ((x >> 16) & 1u);          // round-to-nearest-even
  return (unsigned short)(x >> 16);
}
static __device__ __forceinline__ float bf2f(unsigned short u) {
  return __uint_as_float(((unsigned int)u) << 16);
}

// ---------------------------------------------------------------------------
// three_nn: exact reference fp32 formula, strict-< insertion (earlier idx wins)
// ---------------------------------------------------------------------------
__global__ __launch_bounds__(256)
void three_nn_kernel(const float* __restrict__ xyz, const float* __restrict__ xyz_prev,
                     int* __restrict__ idx_out, float* __restrict__ wgt_out) {
  __shared__ __align__(16) float4 pk[MPTS];
  const int b = blockIdx.y;
  const int tid = threadIdx.x;
  for (int j = tid; j < MPTS; j += 256) {
    float x = xyz_prev[((size_t)b*MPTS + j)*3 + 0];
    float y = xyz_prev[((size_t)b*MPTS + j)*3 + 1];
    float z = xyz_prev[((size_t)b*MPTS + j)*3 + 2];
    float s = __fadd_rn(__fadd_rn(__fmul_rn(x,x), __fmul_rn(y,y)), __fmul_rn(z,z));
    pk[j] = make_float4(x, y, z, s);
  }
  __syncthreads();
  const int n = blockIdx.x*256 + tid;
  const size_t qoff = ((size_t)b*NPTS + n)*3;
  const float qx = xyz[qoff], qy = xyz[qoff+1], qz = xyz[qoff+2];
  const float squ = __fadd_rn(__fadd_rn(__fmul_rn(qx,qx), __fmul_rn(qy,qy)), __fmul_rn(qz,qz));

  float d0 = 3.4e38f, d1 = 3.4e38f, d2v = 3.4e38f;
  int j0 = 0, j1 = 0, j2 = 0;
  for (int m = 0; m < MPTS; m += 16) {
    float dd[16];
    #pragma unroll
    for (int u = 0; u < 16; ++u) {
      const float4 p = pk[m + u];
      float dot = __fadd_rn(__fadd_rn(__fmul_rn(qx,p.x), __fmul_rn(qy,p.y)), __fmul_rn(qz,p.z));
      dd[u] = __fsub_rn(__fadd_rn(squ, p.w), __fmul_rn(2.0f, dot));
    }
    float mn = dd[0];
    #pragma unroll
    for (int u = 1; u < 16; ++u) mn = fminf(mn, dd[u]);
    if (mn < d2v) {                          // exec-mask skip for most batches
      #pragma unroll
      for (int u = 0; u < 16; ++u) {
        const float v = dd[u];
        if (v < d2v) {
          if (v < d1) {
            d2v = d1; j2 = j1;
            if (v < d0) { d1 = d0; j1 = j0; d0 = v; j0 = m + u; }
            else        { d1 = v;  j1 = m + u; }
          } else { d2v = v; j2 = m + u; }
        }
      }
    }
  }
  const float s0 = sqrtf(fmaxf(d0, 0.f));
  const float s1 = sqrtf(fmaxf(d1, 0.f));
  const float s2 = sqrtf(fmaxf(d2v, 0.f));
  const float i0 = 1.f/(s0 + 1e-8f), i1 = 1.f/(s1 + 1e-8f), i2 = 1.f/(s2 + 1e-8f);
  const float sum = i0 + i1 + i2;
  const size_t o = ((size_t)b*NPTS + n)*3;
  idx_out[o] = j0; idx_out[o+1] = j1; idx_out[o+2] = j2;
  wgt_out[o] = i0/sum; wgt_out[o+1] = i1/sum; wgt_out[o+2] = i2/sum;
}

// ---------------------------------------------------------------------------
// fp32 -> bf16 flat convert (for weights)
// ---------------------------------------------------------------------------
__global__ __launch_bounds__(256)
void cvt_kernel(const float* __restrict__ s, unsigned short* __restrict__ d, int n) {
  int t = blockIdx.x*256 + threadIdx.x;
  if (t < n) d[t] = f2bf(s[t]);
}

// ---------------------------------------------------------------------------
// Generic [b][c][SRCW] fp32 -> dst[b][n][DOFF + c] bf16 tiled transpose.
// ---------------------------------------------------------------------------
template<int SRCW, int DPITCH, int DOFF>
__global__ __launch_bounds__(256)
void trans_bf16_kernel(const float* __restrict__ src, unsigned short* __restrict__ dst) {
  __shared__ __align__(16) unsigned short St[64][72];
  const int tid = threadIdx.x;
  const int n0 = blockIdx.x*64, c0 = blockIdx.y*64, b = blockIdx.z;
  const int cl = tid >> 2;
  #pragma unroll
  for (int i = 0; i < 4; ++i) {
    int nl = (tid & 3)*16 + i*4;
    float4 v = *(const float4*)&src[((size_t)(b*256 + c0 + cl))*SRCW + n0 + nl];
    St[cl][nl]   = f2bf(v.x); St[cl][nl+1] = f2bf(v.y);
    St[cl][nl+2] = f2bf(v.z); St[cl][nl+3] = f2bf(v.w);
  }
  __syncthreads();
  #pragma unroll
  for (int i = 0; i < 2; ++i) {
    int u = tid + i*256;
    int nl = u >> 3, c8 = (u & 7)*8;
    unsigned short tmp[8];
    #pragma unroll
    for (int j = 0; j < 8; ++j) tmp[j] = St[c8 + j][nl];
    *(uint4*)&dst[((size_t)(b*SRCW + n0 + nl))*DPITCH + DOFF + c0 + c8] = *(uint4*)tmp;
  }
}

// ---------------------------------------------------------------------------
// interpolate from row-major fpT[b][m][256] bf16 -> X1t[b][n][0:256] bf16.
// ---------------------------------------------------------------------------
__global__ __launch_bounds__(256)
void interp_t_kernel(const unsigned short* __restrict__ fpT, const int* __restrict__ idx,
                     const float* __restrict__ wgt, unsigned short* __restrict__ X1t) {
  const int tid = threadIdx.x;
  const int b = blockIdx.y;
  const int n = blockIdx.x*8 + (tid >> 5);      // 8 points per block
  const int c8 = (tid & 31)*8;                  // this lane's 8-channel slice
  const size_t p = ((size_t)b*NPTS + n)*3;
  const int i0 = idx[p], i1 = idx[p+1], i2 = idx[p+2];
  const float w0 = wgt[p], w1 = wgt[p+1], w2 = wgt[p+2];
  const unsigned short* fb = fpT + (size_t)b*MPTS*256 + c8;
  uint4 a0 = *(const uint4*)&fb[(size_t)i0*256];
  uint4 a1 = *(const uint4*)&fb[(size_t)i1*256];
  uint4 a2 = *(const uint4*)&fb[(size_t)i2*256];
  const unsigned short* u0 = (const unsigned short*)&a0;
  const unsigned short* u1 = (const unsigned short*)&a1;
  const unsigned short* u2 = (const unsigned short*)&a2;
  unsigned short r[8];
  #pragma unroll
  for (int j = 0; j < 8; ++j) {
    float v = bf2f(u0[j])*w0 + bf2f(u1[j])*w1 + bf2f(u2[j])*w2;
    r[j] = f2bf(v);
  }
  *(uint4*)&X1t[((size_t)b*NPTS + n)*512 + c8] = *(uint4*)r;
}

// ---------------------------------------------------------------------------
// MFMA GEMM: Y[b][n][o] = sum_k W[o][k] * Xt[b][n][k]  (all bf16, fp32 acc)
// 512 thr (8 waves = 4 o-groups x 2 n-groups), tile [256 o][128 n], BK=32.
// MODE 1: fused BN1+ReLU on X during staging.
// BN stats: shfl-reduce -> LDS atomics -> ONE per-block partial write
// (part[blk][0:256]=sum, [256:512]=sq). NO global atomics (R4: 524k
// device-scope atomicAdds on 512 hot addrs cost ~130 us/dispatch).
// ---------------------------------------------------------------------------
template<int KD, int MODE>
__global__ __launch_bounds__(512)
void gemm_t_kernel(const unsigned short* __restrict__ W, const unsigned short* __restrict__ X,
                   const float* __restrict__ bias, const float* __restrict__ scl,
                   const float* __restrict__ shf, unsigned short* __restrict__ Y,
                   float* __restrict__ part) {
  __shared__ __align__(16) unsigned short Ws[256*PITCH];
  __shared__ __align__(16) unsigned short Xs[128*PITCH];
  __shared__ float lsum[256], lsq[256];
  const int tid = threadIdx.x;
  const int b = blockIdx.y, n0 = blockIdx.x*128;
  const int row = tid >> 2, seg = tid & 3;          // 128 rows x 4 16B-segments
  const unsigned short* Xb = X + (size_t)(b*NPTS + n0)*KD;

  if (tid < 256) { lsum[tid] = 0.f; lsq[tid] = 0.f; }   // synced by 1st barrier

  uint4 wv0 = *(const uint4*)&W[(size_t)row*KD + seg*8];
  uint4 wv1 = *(const uint4*)&W[(size_t)(row+128)*KD + seg*8];
  uint4 xv  = *(const uint4*)&Xb[(size_t)row*KD + seg*8];

  f32x4 acc[4][4];
  #pragma unroll
  for (int i = 0; i < 4; ++i)
    #pragma unroll
    for (int j = 0; j < 4; ++j) acc[i][j] = (f32x4){0.f,0.f,0.f,0.f};

  const int lane = tid & 63, l16 = lane & 15, quad = lane >> 4;
  const int wave = tid >> 6, wo = wave >> 1, wn = wave & 1;

  for (int kt = 0; kt < KD/32; ++kt) {
    __syncthreads();
    *(uint4*)&Ws[row*PITCH + seg*8]       = wv0;
    *(uint4*)&Ws[(row+128)*PITCH + seg*8] = wv1;
    if (MODE == 0) {
      *(uint4*)&Xs[row*PITCH + seg*8] = xv;
    } else {
      const int kc = kt*32 + seg*8;
      float4 s0 = *(const float4*)&scl[kc], s1 = *(const float4*)&scl[kc+4];
      float4 h0 = *(const float4*)&shf[kc], h1 = *(const float4*)&shf[kc+4];
      const unsigned short* xu = (const unsigned short*)&xv;
      unsigned short t[8];
      t[0] = f2bf(fmaxf(fmaf(bf2f(xu[0]), s0.x, h0.x), 0.f));
      t[1] = f2bf(fmaxf(fmaf(bf2f(xu[1]), s0.y, h0.y), 0.f));
      t[2] = f2bf(fmaxf(fmaf(bf2f(xu[2]), s0.z, h0.z), 0.f));
      t[3] = f2bf(fmaxf(fmaf(bf2f(xu[3]), s0.w, h0.w), 0.f));
      t[4] = f2bf(fmaxf(fmaf(bf2f(xu[4]), s1.x, h1.x), 0.f));
      t[5] = f2bf(fmaxf(fmaf(bf2f(xu[5]), s1.y, h1.y), 0.f));
      t[6] = f2bf(fmaxf(fmaf(bf2f(xu[6]), s1.z, h1.z), 0.f));
      t[7] = f2bf(fmaxf(fmaf(bf2f(xu[7]), s1.w, h1.w), 0.f));
      *(uint4*)&Xs[row*PITCH + seg*8] = *(uint4*)t;
    }
    __syncthreads();
    if (kt + 1 < KD/32) {
      const int k0 = (kt+1)*32;
      wv0 = *(const uint4*)&W[(size_t)row*KD + k0 + seg*8];
      wv1 = *(const uint4*)&W[(size_t)(row+128)*KD + k0 + seg*8];
      xv  = *(const uint4*)&Xb[(size_t)row*KD + k0 + seg*8];
    }
    bf16x8 af[4], bfr[4];
    #pragma unroll
    for (int to = 0; to < 4; ++to)
      af[to] = *(const bf16x8*)&Ws[(wo*64 + to*16 + l16)*PITCH + quad*8];
    #pragma unroll
    for (int tn = 0; tn < 4; ++tn)
      bfr[tn] = *(const bf16x8*)&Xs[(wn*64 + tn*16 + l16)*PITCH + quad*8];
    #pragma unroll
    for (int to = 0; to < 4; ++to)
      #pragma unroll
      for (int tn = 0; tn < 4; ++tn)
        acc[to][tn] = __builtin_amdgcn_mfma_f32_16x16x32_bf16(af[to], bfr[tn], acc[to][tn], 0, 0, 0);
  }

  // epilogue: bias, BN partial stats (shuffle over 16 n-lanes -> LDS atomics)
  #pragma unroll
  for (int to = 0; to < 4; ++to) {
    #pragma unroll
    for (int r = 0; r < 4; ++r) {
      const int o = wo*64 + to*16 + quad*4 + r;
      const float bv = bias[o];
      float p = 0.f, q = 0.f;
      #pragma unroll
      for (int tn = 0; tn < 4; ++tn) {
        float v = acc[to][tn][r] + bv;
        acc[to][tn][r] = v;
        p += v; q = fmaf(v, v, q);
      }
      #pragma unroll
      for (int m = 1; m < 16; m <<= 1) { p += __shfl_xor(p, m); q += __shfl_xor(q, m); }
      if (l16 == 0) { atomicAdd(&lsum[o], p); atomicAdd(&lsq[o], q); }
    }
  }
  // store y^T bf16: [n][o], 8B per lane
  #pragma unroll
  for (int to = 0; to < 4; ++to)
    #pragma unroll
    for (int tn = 0; tn < 4; ++tn) {
      const int n = n0 + wn*64 + tn*16 + l16;
      const int o = wo*64 + to*16 + quad*4;
      unsigned int lo = (unsigned)f2bf(acc[to][tn][0]) | ((unsigned)f2bf(acc[to][tn][1]) << 16);
      unsigned int hi = (unsigned)f2bf(acc[to][tn][2]) | ((unsigned)f2bf(acc[to][tn][3]) << 16);
      *(uint2*)&Y[((size_t)(b*NPTS + n))*256 + o] = make_uint2(lo, hi);
    }
  __syncthreads();
  if (tid < 256) {
    const int blk = b*gridDim.x + blockIdx.x;
    part[(size_t)blk*512 + tid]       = lsum[tid];
    part[(size_t)blk*512 + 256 + tid] = lsq[tid];
  }
}

// ---------------------------------------------------------------------------
// Reduce per-block BN partials (512 blocks x [256 sum | 256 sq]) + finalize.
// 1024 threads: 4 groups of 256, coalesced row reads.
// ---------------------------------------------------------------------------
__global__ __launch_bounds__(1024)
void bn_reduce_kernel(const float* __restrict__ part, const float* __restrict__ g,
                      const float* __restrict__ beta, float* __restrict__ scl,
                      float* __restrict__ shf) {
  __shared__ float ls[4][256], lq[4][256];
  const int o = threadIdx.x & 255, grp = threadIdx.x >> 8;
  float s = 0.f, q = 0.f;
  for (int r = grp; r < 512; r += 4) {
    s += part[(size_t)r*512 + o];
    q += part[(size_t)r*512 + 256 + o];
  }
  ls[grp][o] = s; lq[grp][o] = q;
  __syncthreads();
  if (threadIdx.x < 256) {
    float ss = ls[0][o] + ls[1][o] + ls[2][o] + ls[3][o];
    float qq = lq[0][o] + lq[1][o] + lq[2][o] + lq[3][o];
    const float inv_n = 1.0f / NSAMP;
    const float mean = ss * inv_n;
    const float var  = qq * inv_n - mean*mean;
    const float sc = g[o] * rsqrtf(var + 1e-5f);
    scl[o] = sc;
    shf[o] = beta[o] - mean * sc;
  }
}

// ---------------------------------------------------------------------------
// Final: y2t[b][n][o] bf16 -> out[b][o][n] fp32 with BN2+ReLU (tiled transpose)
// ---------------------------------------------------------------------------
__global__ __launch_bounds__(256)
void bn2_t_kernel(const unsigned short* __restrict__ Yt, const float* __restrict__ scl,
                  const float* __restrict__ shf, float* __restrict__ out) {
  __shared__ __align__(16) unsigned short T[64][72];
  const int tid = threadIdx.x;
  const int n0 = blockIdx.x*64, o0 = blockIdx.y*64, b = blockIdx.z;
  #pragma unroll
  for (int i = 0; i < 2; ++i) {
    int u = tid + i*256;
    int nl = u >> 3, o8 = (u & 7)*8;
    uint4 v = *(const uint4*)&Yt[((size_t)(b*NPTS + n0 + nl))*256 + o0 + o8];
    *(uint4*)&T[nl][o8] = v;
  }
  __syncthreads();
  #pragma unroll
  for (int i = 0; i < 4; ++i) {
    int u = tid + i*256;
    int ol = u >> 4, n4 = (u & 15)*4;
    const float s = scl[o0+ol], h = shf[o0+ol];
    float4 v;
    v.x = fmaxf(fmaf(bf2f(T[n4  ][ol]), s, h), 0.f);
    v.y = fmaxf(fmaf(bf2f(T[n4+1][ol]), s, h), 0.f);
    v.z = fmaxf(fmaf(bf2f(T[n4+2][ol]), s, h), 0.f);
    v.w = fmaxf(fmaf(bf2f(T[n4+3][ol]), s, h), 0.f);
    *(float4*)&out[((size_t)(b*256 + o0 + ol))*NPTS + n0 + n4] = v;
  }
}

// ---------------------------------------------------------------------------
// ws layout (bytes):
//   0        idx   int32[8*8192*3]          786432
//   786432   wgt   f32 [8*8192*3]           786432
//   1572864  bn    f32 [2048]                 8192  (scl/shf x2)
//   1581056  w1b   bf16[256*512]            262144
//   1843200  w2b   bf16[256*256]            131072
//   2097152  X1t   bf16[8*8192*512]       67108864  (later reused as y2t)
// d_out (64 MB f32 out buffer) doubles as scratch:
//   [0,32MB)    y1t  bf16[8*8192*256]
//   [32,40MB)   fpT  bf16[8*2048*256]
//   [40,41MB)   part f32[512*512]  (per-block BN partials, reused by GEMM2)
// ---------------------------------------------------------------------------
extern "C" void kernel_launch(void* const* d_in, const int* in_sizes, int n_in,
                              void* d_out, int out_size, void* d_ws, size_t ws_size,
                              hipStream_t stream) {
  const float* xyz           = (const float*)d_in[0];
  const float* xyz_prev      = (const float*)d_in[1];
  const float* features      = (const float*)d_in[2];
  const float* features_prev = (const float*)d_in[3];
  const float* w1    = (const float*)d_in[4];
  const float* b1    = (const float*)d_in[5];
  const float* g1    = (const float*)d_in[6];
  const float* beta1 = (const float*)d_in[7];
  const float* w2    = (const float*)d_in[8];
  const float* b2    = (const float*)d_in[9];
  const float* g2    = (const float*)d_in[10];
  const float* beta2 = (const float*)d_in[11];
  float* out = (float*)d_out;

  char* ws = (char*)d_ws;
  int*            idxb = (int*)ws;
  float*          wgtb = (float*)(ws + 786432);
  float*          bn   = (float*)(ws + 1572864);
  unsigned short* w1b  = (unsigned short*)(ws + 1581056);
  unsigned short* w2b  = (unsigned short*)(ws + 1843200);
  unsigned short* X1t  = (unsigned short*)(ws + 2097152);
  unsigned short* y2t  = X1t;                      // X1t dead after GEMM1
  unsigned short* y1t  = (unsigned short*)d_out;   // scratch until final kernel
  unsigned short* fpT  = (unsigned short*)((char*)d_out + 33554432);
  float*          part = (float*)((char*)d_out + 41943040);

  float* bn1_scl = bn;        float* bn1_shf = bn + 256;
  float* bn2_scl = bn + 512;  float* bn2_shf = bn + 768;

  cvt_kernel<<<512, 256, 0, stream>>>(w1, w1b, 131072);
  cvt_kernel<<<256, 256, 0, stream>>>(w2, w2b, 65536);

  three_nn_kernel<<<dim3(NPTS/256, BDIM), 256, 0, stream>>>(xyz, xyz_prev, idxb, wgtb);

  // features -> X1t[:, :, 256:512]
  trans_bf16_kernel<NPTS, 512, 256><<<dim3(NPTS/64, 4, BDIM), 256, 0, stream>>>(features, X1t);
  // features_prev -> fpT row-major
  trans_bf16_kernel<MPTS, 256, 0><<<dim3(MPTS/64, 4, BDIM), 256, 0, stream>>>(features_prev, fpT);

  interp_t_kernel<<<dim3(NPTS/8, BDIM), 256, 0, stream>>>(fpT, idxb, wgtb, X1t);

  gemm_t_kernel<512, 0><<<dim3(NPTS/128, BDIM), 512, 0, stream>>>(
      w1b, X1t, b1, nullptr, nullptr, y1t, part);
  bn_reduce_kernel<<<1, 1024, 0, stream>>>(part, g1, beta1, bn1_scl, bn1_shf);

  gemm_t_kernel<256, 1><<<dim3(NPTS/128, BDIM), 512, 0, stream>>>(
      w2b, y1t, b2, bn1_scl, bn1_shf, y2t, part);
  bn_reduce_kernel<<<1, 1024, 0, stream>>>(part, g2, beta2, bn2_scl, bn2_shf);

  bn2_t_kernel<<<dim3(NPTS/64, 4, BDIM), 256, 0, stream>>>(y2t, bn2_scl, bn2_shf, out);
}

// Round 6
// 376.762 us; speedup vs baseline: 2.1898x; 1.1796x over previous
//
#include <hip/hip_runtime.h>

#define BDIM 8
#define NPTS 8192
#define MPTS 2048
#define NCHUNK 8
#define CHSZ 256          // MPTS / NCHUNK
#define NSAMP 65536.0f
#define PITCH 40   // GEMM LDS row pitch in halves (80 B) -> 2-way max bank aliasing

typedef __attribute__((ext_vector_type(8))) short bf16x8;
typedef __attribute__((ext_vector_type(4))) float f32x4;

static __device__ __forceinline__ unsigned short f2bf(float f) {
  unsigned int x = __float_as_uint(f);
  x += 0x7FFFu + ((x >> 16) & 1u);          // round-to-nearest-even
  return (unsigned short)(x >> 16);
}
static __device__ __forceinline__ float bf2f(unsigned short u) {
  return __uint_as_float(((unsigned int)u) << 16);
}

// ---------------------------------------------------------------------------
// three_nn partial: each block scans ONE 256-candidate chunk for 256 queries.
// Exact reference fp32 distance formula; strict-< insertion (earlier idx wins).
// Grid (NPTS/256, NCHUNK, B) = 2048 blocks -> 8 blocks/CU (vs 1 in R5).
// ---------------------------------------------------------------------------
__global__ __launch_bounds__(256)
void three_nn_part_kernel(const float* __restrict__ xyz, const float* __restrict__ xyz_prev,
                          float4* __restrict__ pd, int4* __restrict__ pi) {
  __shared__ __align__(16) float4 pk[CHSZ];
  const int tid = threadIdx.x;
  const int ch = blockIdx.y, b = blockIdx.z;
  const int mbase = ch*CHSZ;
  {
    const int j = mbase + tid;
    float x = xyz_prev[((size_t)b*MPTS + j)*3 + 0];
    float y = xyz_prev[((size_t)b*MPTS + j)*3 + 1];
    float z = xyz_prev[((size_t)b*MPTS + j)*3 + 2];
    float s = __fadd_rn(__fadd_rn(__fmul_rn(x,x), __fmul_rn(y,y)), __fmul_rn(z,z));
    pk[tid] = make_float4(x, y, z, s);
  }
  __syncthreads();
  const int n = blockIdx.x*256 + tid;
  const size_t qoff = ((size_t)b*NPTS + n)*3;
  const float qx = xyz[qoff], qy = xyz[qoff+1], qz = xyz[qoff+2];
  const float squ = __fadd_rn(__fadd_rn(__fmul_rn(qx,qx), __fmul_rn(qy,qy)), __fmul_rn(qz,qz));

  float d0 = 3.4e38f, d1 = 3.4e38f, d2v = 3.4e38f;
  int j0 = 0, j1 = 0, j2 = 0;
  for (int m = 0; m < CHSZ; m += 16) {
    float dd[16];
    #pragma unroll
    for (int u = 0; u < 16; ++u) {
      const float4 p = pk[m + u];
      float dot = __fadd_rn(__fadd_rn(__fmul_rn(qx,p.x), __fmul_rn(qy,p.y)), __fmul_rn(qz,p.z));
      dd[u] = __fsub_rn(__fadd_rn(squ, p.w), __fmul_rn(2.0f, dot));
    }
    float mn = dd[0];
    #pragma unroll
    for (int u = 1; u < 16; ++u) mn = fminf(mn, dd[u]);
    if (mn < d2v) {                          // exec-mask skip for most batches
      #pragma unroll
      for (int u = 0; u < 16; ++u) {
        const float v = dd[u];
        if (v < d2v) {
          if (v < d1) {
            d2v = d1; j2 = j1;
            if (v < d0) { d1 = d0; j1 = j0; d0 = v; j0 = mbase + m + u; }
            else        { d1 = v;  j1 = mbase + m + u; }
          } else { d2v = v; j2 = mbase + m + u; }
        }
      }
    }
  }
  const size_t q = (size_t)b*NPTS + n;
  pd[(size_t)ch*(BDIM*NPTS) + q] = make_float4(d0, d1, d2v, 0.f);
  pi[(size_t)ch*(BDIM*NPTS) + q] = make_int4(j0, j1, j2, 0);
}

// ---------------------------------------------------------------------------
// Merge 8 per-chunk top-3 partials -> final idx/wgt. Ascending chunk order +
// strict-< insertion preserves reference (full-scan) tie semantics.
// ---------------------------------------------------------------------------
__global__ __launch_bounds__(256)
void nn_merge_kernel(const float4* __restrict__ pd, const int4* __restrict__ pi,
                     int* __restrict__ idx_out, float* __restrict__ wgt_out) {
  const size_t q = (size_t)blockIdx.x*256 + threadIdx.x;   // 0 .. B*N-1
  float d0 = 3.4e38f, d1 = 3.4e38f, d2v = 3.4e38f;
  int j0 = 0, j1 = 0, j2 = 0;
  #pragma unroll
  for (int c = 0; c < NCHUNK; ++c) {
    const float4 dv = pd[(size_t)c*(BDIM*NPTS) + q];
    const int4   iv = pi[(size_t)c*(BDIM*NPTS) + q];
    const float dl[3] = {dv.x, dv.y, dv.z};
    const int   jl[3] = {iv.x, iv.y, iv.z};
    #pragma unroll
    for (int t = 0; t < 3; ++t) {
      const float v = dl[t]; const int j = jl[t];
      if (v < d2v) {
        if (v < d1) {
          d2v = d1; j2 = j1;
          if (v < d0) { d1 = d0; j1 = j0; d0 = v; j0 = j; }
          else        { d1 = v;  j1 = j; }
        } else { d2v = v; j2 = j; }
      }
    }
  }
  const float s0 = sqrtf(fmaxf(d0, 0.f));
  const float s1 = sqrtf(fmaxf(d1, 0.f));
  const float s2 = sqrtf(fmaxf(d2v, 0.f));
  const float i0 = 1.f/(s0 + 1e-8f), i1 = 1.f/(s1 + 1e-8f), i2 = 1.f/(s2 + 1e-8f);
  const float sum = i0 + i1 + i2;
  idx_out[q*3] = j0; idx_out[q*3+1] = j1; idx_out[q*3+2] = j2;
  wgt_out[q*3] = i0/sum; wgt_out[q*3+1] = i1/sum; wgt_out[q*3+2] = i2/sum;
}

// ---------------------------------------------------------------------------
// fp32 -> bf16 flat convert (for weights)
// ---------------------------------------------------------------------------
__global__ __launch_bounds__(256)
void cvt_kernel(const float* __restrict__ s, unsigned short* __restrict__ d, int n) {
  int t = blockIdx.x*256 + threadIdx.x;
  if (t < n) d[t] = f2bf(s[t]);
}

// ---------------------------------------------------------------------------
// Generic [b][c][SRCW] fp32 -> dst[b][n][DOFF + c] bf16 tiled transpose.
// ---------------------------------------------------------------------------
template<int SRCW, int DPITCH, int DOFF>
__global__ __launch_bounds__(256)
void trans_bf16_kernel(const float* __restrict__ src, unsigned short* __restrict__ dst) {
  __shared__ __align__(16) unsigned short St[64][72];
  const int tid = threadIdx.x;
  const int n0 = blockIdx.x*64, c0 = blockIdx.y*64, b = blockIdx.z;
  const int cl = tid >> 2;
  #pragma unroll
  for (int i = 0; i < 4; ++i) {
    int nl = (tid & 3)*16 + i*4;
    float4 v = *(const float4*)&src[((size_t)(b*256 + c0 + cl))*SRCW + n0 + nl];
    St[cl][nl]   = f2bf(v.x); St[cl][nl+1] = f2bf(v.y);
    St[cl][nl+2] = f2bf(v.z); St[cl][nl+3] = f2bf(v.w);
  }
  __syncthreads();
  #pragma unroll
  for (int i = 0; i < 2; ++i) {
    int u = tid + i*256;
    int nl = u >> 3, c8 = (u & 7)*8;
    unsigned short tmp[8];
    #pragma unroll
    for (int j = 0; j < 8; ++j) tmp[j] = St[c8 + j][nl];
    *(uint4*)&dst[((size_t)(b*SRCW + n0 + nl))*DPITCH + DOFF + c0 + c8] = *(uint4*)tmp;
  }
}

// ---------------------------------------------------------------------------
// interpolate from row-major fpT[b][m][256] bf16 -> X1t[b][n][0:256] bf16.
// ---------------------------------------------------------------------------
__global__ __launch_bounds__(256)
void interp_t_kernel(const unsigned short* __restrict__ fpT, const int* __restrict__ idx,
                     const float* __restrict__ wgt, unsigned short* __restrict__ X1t) {
  const int tid = threadIdx.x;
  const int b = blockIdx.y;
  const int n = blockIdx.x*8 + (tid >> 5);      // 8 points per block
  const int c8 = (tid & 31)*8;                  // this lane's 8-channel slice
  const size_t p = ((size_t)b*NPTS + n)*3;
  const int i0 = idx[p], i1 = idx[p+1], i2 = idx[p+2];
  const float w0 = wgt[p], w1 = wgt[p+1], w2 = wgt[p+2];
  const unsigned short* fb = fpT + (size_t)b*MPTS*256 + c8;
  uint4 a0 = *(const uint4*)&fb[(size_t)i0*256];
  uint4 a1 = *(const uint4*)&fb[(size_t)i1*256];
  uint4 a2 = *(const uint4*)&fb[(size_t)i2*256];
  const unsigned short* u0 = (const unsigned short*)&a0;
  const unsigned short* u1 = (const unsigned short*)&a1;
  const unsigned short* u2 = (const unsigned short*)&a2;
  unsigned short r[8];
  #pragma unroll
  for (int j = 0; j < 8; ++j) {
    float v = bf2f(u0[j])*w0 + bf2f(u1[j])*w1 + bf2f(u2[j])*w2;
    r[j] = f2bf(v);
  }
  *(uint4*)&X1t[((size_t)b*NPTS + n)*512 + c8] = *(uint4*)r;
}

// ---------------------------------------------------------------------------
// MFMA GEMM: Y[b][n][o] = sum_k W[o][k] * Xt[b][n][k]  (all bf16, fp32 acc)
// 512 thr (8 waves = 4 o-groups x 2 n-groups), tile [256 o][128 n], BK=32.
// MODE 1: fused BN1+ReLU on X during staging.
// BN stats: shfl-reduce -> LDS atomics -> ONE per-block partial write.
// ---------------------------------------------------------------------------
template<int KD, int MODE>
__global__ __launch_bounds__(512)
void gemm_t_kernel(const unsigned short* __restrict__ W, const unsigned short* __restrict__ X,
                   const float* __restrict__ bias, const float* __restrict__ scl,
                   const float* __restrict__ shf, unsigned short* __restrict__ Y,
                   float* __restrict__ part) {
  __shared__ __align__(16) unsigned short Ws[256*PITCH];
  __shared__ __align__(16) unsigned short Xs[128*PITCH];
  __shared__ float lsum[256], lsq[256];
  const int tid = threadIdx.x;
  const int b = blockIdx.y, n0 = blockIdx.x*128;
  const int row = tid >> 2, seg = tid & 3;          // 128 rows x 4 16B-segments
  const unsigned short* Xb = X + (size_t)(b*NPTS + n0)*KD;

  if (tid < 256) { lsum[tid] = 0.f; lsq[tid] = 0.f; }   // synced by 1st barrier

  uint4 wv0 = *(const uint4*)&W[(size_t)row*KD + seg*8];
  uint4 wv1 = *(const uint4*)&W[(size_t)(row+128)*KD + seg*8];
  uint4 xv  = *(const uint4*)&Xb[(size_t)row*KD + seg*8];

  f32x4 acc[4][4];
  #pragma unroll
  for (int i = 0; i < 4; ++i)
    #pragma unroll
    for (int j = 0; j < 4; ++j) acc[i][j] = (f32x4){0.f,0.f,0.f,0.f};

  const int lane = tid & 63, l16 = lane & 15, quad = lane >> 4;
  const int wave = tid >> 6, wo = wave >> 1, wn = wave & 1;

  for (int kt = 0; kt < KD/32; ++kt) {
    __syncthreads();
    *(uint4*)&Ws[row*PITCH + seg*8]       = wv0;
    *(uint4*)&Ws[(row+128)*PITCH + seg*8] = wv1;
    if (MODE == 0) {
      *(uint4*)&Xs[row*PITCH + seg*8] = xv;
    } else {
      const int kc = kt*32 + seg*8;
      float4 s0 = *(const float4*)&scl[kc], s1 = *(const float4*)&scl[kc+4];
      float4 h0 = *(const float4*)&shf[kc], h1 = *(const float4*)&shf[kc+4];
      const unsigned short* xu = (const unsigned short*)&xv;
      unsigned short t[8];
      t[0] = f2bf(fmaxf(fmaf(bf2f(xu[0]), s0.x, h0.x), 0.f));
      t[1] = f2bf(fmaxf(fmaf(bf2f(xu[1]), s0.y, h0.y), 0.f));
      t[2] = f2bf(fmaxf(fmaf(bf2f(xu[2]), s0.z, h0.z), 0.f));
      t[3] = f2bf(fmaxf(fmaf(bf2f(xu[3]), s0.w, h0.w), 0.f));
      t[4] = f2bf(fmaxf(fmaf(bf2f(xu[4]), s1.x, h1.x), 0.f));
      t[5] = f2bf(fmaxf(fmaf(bf2f(xu[5]), s1.y, h1.y), 0.f));
      t[6] = f2bf(fmaxf(fmaf(bf2f(xu[6]), s1.z, h1.z), 0.f));
      t[7] = f2bf(fmaxf(fmaf(bf2f(xu[7]), s1.w, h1.w), 0.f));
      *(uint4*)&Xs[row*PITCH + seg*8] = *(uint4*)t;
    }
    __syncthreads();
    if (kt + 1 < KD/32) {
      const int k0 = (kt+1)*32;
      wv0 = *(const uint4*)&W[(size_t)row*KD + k0 + seg*8];
      wv1 = *(const uint4*)&W[(size_t)(row+128)*KD + k0 + seg*8];
      xv  = *(const uint4*)&Xb[(size_t)row*KD + k0 + seg*8];
    }
    bf16x8 af[4], bfr[4];
    #pragma unroll
    for (int to = 0; to < 4; ++to)
      af[to] = *(const bf16x8*)&Ws[(wo*64 + to*16 + l16)*PITCH + quad*8];
    #pragma unroll
    for (int tn = 0; tn < 4; ++tn)
      bfr[tn] = *(const bf16x8*)&Xs[(wn*64 + tn*16 + l16)*PITCH + quad*8];
    #pragma unroll
    for (int to = 0; to < 4; ++to)
      #pragma unroll
      for (int tn = 0; tn < 4; ++tn)
        acc[to][tn] = __builtin_amdgcn_mfma_f32_16x16x32_bf16(af[to], bfr[tn], acc[to][tn], 0, 0, 0);
  }

  // epilogue: bias, BN partial stats (shuffle over 16 n-lanes -> LDS atomics)
  #pragma unroll
  for (int to = 0; to < 4; ++to) {
    #pragma unroll
    for (int r = 0; r < 4; ++r) {
      const int o = wo*64 + to*16 + quad*4 + r;
      const float bv = bias[o];
      float p = 0.f, q = 0.f;
      #pragma unroll
      for (int tn = 0; tn < 4; ++tn) {
        float v = acc[to][tn][r] + bv;
        acc[to][tn][r] = v;
        p += v; q = fmaf(v, v, q);
      }
      #pragma unroll
      for (int m = 1; m < 16; m <<= 1) { p += __shfl_xor(p, m); q += __shfl_xor(q, m); }
      if (l16 == 0) { atomicAdd(&lsum[o], p); atomicAdd(&lsq[o], q); }
    }
  }
  // store y^T bf16: [n][o], 8B per lane
  #pragma unroll
  for (int to = 0; to < 4; ++to)
    #pragma unroll
    for (int tn = 0; tn < 4; ++tn) {
      const int n = n0 + wn*64 + tn*16 + l16;
      const int o = wo*64 + to*16 + quad*4;
      unsigned int lo = (unsigned)f2bf(acc[to][tn][0]) | ((unsigned)f2bf(acc[to][tn][1]) << 16);
      unsigned int hi = (unsigned)f2bf(acc[to][tn][2]) | ((unsigned)f2bf(acc[to][tn][3]) << 16);
      *(uint2*)&Y[((size_t)(b*NPTS + n))*256 + o] = make_uint2(lo, hi);
    }
  __syncthreads();
  if (tid < 256) {
    const int blk = b*gridDim.x + blockIdx.x;
    part[(size_t)blk*512 + tid]       = lsum[tid];
    part[(size_t)blk*512 + 256 + tid] = lsq[tid];
  }
}

// ---------------------------------------------------------------------------
// Reduce per-block BN partials (512 blocks x [256 sum | 256 sq]) + finalize.
// ---------------------------------------------------------------------------
__global__ __launch_bounds__(1024)
void bn_reduce_kernel(const float* __restrict__ part, const float* __restrict__ g,
                      const float* __restrict__ beta, float* __restrict__ scl,
                      float* __restrict__ shf) {
  __shared__ float ls[4][256], lq[4][256];
  const int o = threadIdx.x & 255, grp = threadIdx.x >> 8;
  float s = 0.f, q = 0.f;
  for (int r = grp; r < 512; r += 4) {
    s += part[(size_t)r*512 + o];
    q += part[(size_t)r*512 + 256 + o];
  }
  ls[grp][o] = s; lq[grp][o] = q;
  __syncthreads();
  if (threadIdx.x < 256) {
    float ss = ls[0][o] + ls[1][o] + ls[2][o] + ls[3][o];
    float qq = lq[0][o] + lq[1][o] + lq[2][o] + lq[3][o];
    const float inv_n = 1.0f / NSAMP;
    const float mean = ss * inv_n;
    const float var  = qq * inv_n - mean*mean;
    const float sc = g[o] * rsqrtf(var + 1e-5f);
    scl[o] = sc;
    shf[o] = beta[o] - mean * sc;
  }
}

// ---------------------------------------------------------------------------
// Final: y2t[b][n][o] bf16 -> out[b][o][n] fp32 with BN2+ReLU (tiled transpose)
// ---------------------------------------------------------------------------
__global__ __launch_bounds__(256)
void bn2_t_kernel(const unsigned short* __restrict__ Yt, const float* __restrict__ scl,
                  const float* __restrict__ shf, float* __restrict__ out) {
  __shared__ __align__(16) unsigned short T[64][72];
  const int tid = threadIdx.x;
  const int n0 = blockIdx.x*64, o0 = blockIdx.y*64, b = blockIdx.z;
  #pragma unroll
  for (int i = 0; i < 2; ++i) {
    int u = tid + i*256;
    int nl = u >> 3, o8 = (u & 7)*8;
    uint4 v = *(const uint4*)&Yt[((size_t)(b*NPTS + n0 + nl))*256 + o0 + o8];
    *(uint4*)&T[nl][o8] = v;
  }
  __syncthreads();
  #pragma unroll
  for (int i = 0; i < 4; ++i) {
    int u = tid + i*256;
    int ol = u >> 4, n4 = (u & 15)*4;
    const float s = scl[o0+ol], h = shf[o0+ol];
    float4 v;
    v.x = fmaxf(fmaf(bf2f(T[n4  ][ol]), s, h), 0.f);
    v.y = fmaxf(fmaf(bf2f(T[n4+1][ol]), s, h), 0.f);
    v.z = fmaxf(fmaf(bf2f(T[n4+2][ol]), s, h), 0.f);
    v.w = fmaxf(fmaf(bf2f(T[n4+3][ol]), s, h), 0.f);
    *(float4*)&out[((size_t)(b*256 + o0 + ol))*NPTS + n0 + n4] = v;
  }
}

// ---------------------------------------------------------------------------
// ws layout (bytes):
//   0        idx   int32[8*8192*3]          786432
//   786432   wgt   f32 [8*8192*3]           786432
//   1572864  bn    f32 [2048]                 8192  (scl/shf x2)
//   1581056  w1b   bf16[256*512]            262144
//   1843200  w2b   bf16[256*256]            131072
//   2097152  X1t   bf16[8*8192*512]       67108864  (later reused as y2t)
// d_out (64 MB f32 out buffer) doubles as scratch:
//   [0,32MB)    y1t  bf16[8*8192*256]
//   [32,40MB)   fpT  bf16[8*2048*256]
//   [40,41MB)   part f32[512*512]
//   [44,52MB)   pd   float4[8][65536]   (nn partial dists)
//   [52,60MB)   pi   int4[8][65536]     (nn partial indices)
// ---------------------------------------------------------------------------
extern "C" void kernel_launch(void* const* d_in, const int* in_sizes, int n_in,
                              void* d_out, int out_size, void* d_ws, size_t ws_size,
                              hipStream_t stream) {
  const float* xyz           = (const float*)d_in[0];
  const float* xyz_prev      = (const float*)d_in[1];
  const float* features      = (const float*)d_in[2];
  const float* features_prev = (const float*)d_in[3];
  const float* w1    = (const float*)d_in[4];
  const float* b1    = (const float*)d_in[5];
  const float* g1    = (const float*)d_in[6];
  const float* beta1 = (const float*)d_in[7];
  const float* w2    = (const float*)d_in[8];
  const float* b2    = (const float*)d_in[9];
  const float* g2    = (const float*)d_in[10];
  const float* beta2 = (const float*)d_in[11];
  float* out = (float*)d_out;

  char* ws = (char*)d_ws;
  int*            idxb = (int*)ws;
  float*          wgtb = (float*)(ws + 786432);
  float*          bn   = (float*)(ws + 1572864);
  unsigned short* w1b  = (unsigned short*)(ws + 1581056);
  unsigned short* w2b  = (unsigned short*)(ws + 1843200);
  unsigned short* X1t  = (unsigned short*)(ws + 2097152);
  unsigned short* y2t  = X1t;                      // X1t dead after GEMM1
  unsigned short* y1t  = (unsigned short*)d_out;   // scratch until final kernel
  unsigned short* fpT  = (unsigned short*)((char*)d_out + 33554432);
  float*          part = (float*)((char*)d_out + 41943040);
  float4*         pd   = (float4*)((char*)d_out + 46137344);
  int4*           pi   = (int4*)((char*)d_out + 54525952);

  float* bn1_scl = bn;        float* bn1_shf = bn + 256;
  float* bn2_scl = bn + 512;  float* bn2_shf = bn + 768;

  cvt_kernel<<<512, 256, 0, stream>>>(w1, w1b, 131072);
  cvt_kernel<<<256, 256, 0, stream>>>(w2, w2b, 65536);

  three_nn_part_kernel<<<dim3(NPTS/256, NCHUNK, BDIM), 256, 0, stream>>>(xyz, xyz_prev, pd, pi);
  nn_merge_kernel<<<(BDIM*NPTS)/256, 256, 0, stream>>>(pd, pi, idxb, wgtb);

  // features -> X1t[:, :, 256:512]
  trans_bf16_kernel<NPTS, 512, 256><<<dim3(NPTS/64, 4, BDIM), 256, 0, stream>>>(features, X1t);
  // features_prev -> fpT row-major
  trans_bf16_kernel<MPTS, 256, 0><<<dim3(MPTS/64, 4, BDIM), 256, 0, stream>>>(features_prev, fpT);

  interp_t_kernel<<<dim3(NPTS/8, BDIM), 256, 0, stream>>>(fpT, idxb, wgtb, X1t);

  gemm_t_kernel<512, 0><<<dim3(NPTS/128, BDIM), 512, 0, stream>>>(
      w1b, X1t, b1, nullptr, nullptr, y1t, part);
  bn_reduce_kernel<<<1, 1024, 0, stream>>>(part, g1, beta1, bn1_scl, bn1_shf);

  gemm_t_kernel<256, 1><<<dim3(NPTS/128, BDIM), 512, 0, stream>>>(
      w2b, y1t, b2, bn1_scl, bn1_shf, y2t, part);
  bn_reduce_kernel<<<1, 1024, 0, stream>>>(part, g2, beta2, bn2_scl, bn2_shf);

  bn2_t_kernel<<<dim3(NPTS/64, 4, BDIM), 256, 0, stream>>>(y2t, bn2_scl, bn2_shf, out);
}